// Round 1
// baseline (2096.649 us; speedup 1.0000x reference)
//
#include <hip/hip_runtime.h>
#include <math.h>

// Bidirectional Mamba: B=4 L=1024 DM=DI=512 N=16 K=4 R=32, fp32.
// Strategy: no flips — backward dir uses anti-causal conv + reverse scan.
// Per direction: xz GEMM -> conv+silu -> xproj GEMM -> dt -> fused scan -> out GEMM (beta=dir).

#define B_ 4
#define L_ 1024
#define DM_ 512
#define DI_ 512
#define NS_ 16
#define KC_ 4
#define RR_ 32
#define M_ (B_ * L_)   // 4096

// ---------------- generic tiled fp32 GEMM: C[M,N] = A[M,K] @ B[K,N] (+C if beta) ----
__global__ __launch_bounds__(256) void gemm_f32(
    const float* __restrict__ A, const float* __restrict__ Bm,
    float* __restrict__ C, int M, int N, int K, int beta)
{
    __shared__ float As[16][65];
    __shared__ float Bs[16][65];
    const int t = threadIdx.x;
    const int bm = blockIdx.y * 64;
    const int bn = blockIdx.x * 64;

    const int lr = t >> 2;          // 0..63  A row within tile
    const int lk = (t & 3) * 4;     // 0,4,8,12
    const int br = t >> 4;          // 0..15  B k-row
    const int bc = (t & 15) * 4;    // 0..60
    const int tm = (t >> 4) * 4;    // 0..60
    const int tn = (t & 15) * 4;

    float acc[4][4] = {};

    for (int k0 = 0; k0 < K; k0 += 16) {
        float4 av = *(const float4*)&A[(size_t)(bm + lr) * K + k0 + lk];
        float4 bv = *(const float4*)&Bm[(size_t)(k0 + br) * N + bn + bc];
        As[lk + 0][lr] = av.x;
        As[lk + 1][lr] = av.y;
        As[lk + 2][lr] = av.z;
        As[lk + 3][lr] = av.w;
        Bs[br][bc + 0] = bv.x;
        Bs[br][bc + 1] = bv.y;
        Bs[br][bc + 2] = bv.z;
        Bs[br][bc + 3] = bv.w;
        __syncthreads();
#pragma unroll
        for (int kk = 0; kk < 16; kk++) {
            float a0 = As[kk][tm + 0], a1 = As[kk][tm + 1];
            float a2 = As[kk][tm + 2], a3 = As[kk][tm + 3];
            float b0 = Bs[kk][tn + 0], b1 = Bs[kk][tn + 1];
            float b2 = Bs[kk][tn + 2], b3 = Bs[kk][tn + 3];
            acc[0][0] += a0 * b0; acc[0][1] += a0 * b1; acc[0][2] += a0 * b2; acc[0][3] += a0 * b3;
            acc[1][0] += a1 * b0; acc[1][1] += a1 * b1; acc[1][2] += a1 * b2; acc[1][3] += a1 * b3;
            acc[2][0] += a2 * b0; acc[2][1] += a2 * b1; acc[2][2] += a2 * b2; acc[2][3] += a2 * b3;
            acc[3][0] += a3 * b0; acc[3][1] += a3 * b1; acc[3][2] += a3 * b2; acc[3][3] += a3 * b3;
        }
        __syncthreads();
    }

#pragma unroll
    for (int i = 0; i < 4; i++) {
        float4* p = (float4*)&C[(size_t)(bm + tm + i) * N + bn + tn];
        float4 v = make_float4(acc[i][0], acc[i][1], acc[i][2], acc[i][3]);
        if (beta) {
            float4 o = *p;
            v.x += o.x; v.y += o.y; v.z += o.z; v.w += o.w;
        }
        *p = v;
    }
}

// ---------------- conv (causal fwd / anticausal bwd) + bias + SiLU -> xs ------------
__global__ __launch_bounds__(256) void conv_silu(
    const float* __restrict__ xz, const float* __restrict__ Wc,
    const float* __restrict__ bc, float* __restrict__ xs, int dir)
{
    int idx = blockIdx.x * 256 + threadIdx.x;       // over M_*512
    int d  = idx & 511;
    int bl = idx >> 9;
    int l  = bl & (L_ - 1);
    int b  = bl >> 10;

    float acc = bc[d];
    if (dir == 0) {
#pragma unroll
        for (int k = 0; k < KC_; k++) {
            int ls = l - 3 + k;
            if (ls >= 0) acc += xz[((size_t)(b * L_ + ls) << 10) + d] * Wc[d * 4 + k];
        }
    } else {
#pragma unroll
        for (int k = 0; k < KC_; k++) {
            int ls = l + 3 - k;
            if (ls < L_) acc += xz[((size_t)(b * L_ + ls) << 10) + d] * Wc[d * 4 + k];
        }
    }
    xs[idx] = acc / (1.f + expf(-acc));   // silu
}

// ---------------- dt = softplus(dt_in @ W_dt + b_dt) -------------------------------
__global__ __launch_bounds__(256) void dt_kernel(
    const float* __restrict__ dbc, const float* __restrict__ Wdt,
    const float* __restrict__ bdt, float* __restrict__ dt)
{
    int idx = blockIdx.x * 256 + threadIdx.x;  // over M_*512
    int d   = idx & 511;
    int row = idx >> 9;
    float acc = bdt[d];
#pragma unroll
    for (int k = 0; k < RR_; k++)
        acc += dbc[row * 64 + k] * Wdt[k * 512 + d];
    // stable softplus
    float sp = (acc > 20.f) ? acc : log1pf(expf(acc));
    dt[idx] = sp;
}

// ---------------- fused selective scan + C-reduce + D skip + z-gate -----------------
// one thread per (b, d, n); 16-lane shfl reduce over n.
__global__ __launch_bounds__(256) void scan_kernel(
    const float* __restrict__ dt, const float* __restrict__ xs,
    const float* __restrict__ dbc, const float* __restrict__ xz,
    const float* __restrict__ A_log, const float* __restrict__ Dp,
    float* __restrict__ ym, int dir)
{
    int t = blockIdx.x * 256 + threadIdx.x;    // 0 .. B_*512*16
    int n = t & 15;
    int d = (t >> 4) & 511;
    int b = t >> 13;

    float Av = -expf(A_log[d * 16 + n]);
    float Dv = Dp[d];
    float h = 0.f;

    for (int i = 0; i < L_; i++) {
        int l = dir ? (L_ - 1 - i) : i;
        int bl = b * L_ + l;
        float dtv = dt[bl * 512 + d];
        float xsv = xs[bl * 512 + d];
        float Bv  = dbc[bl * 64 + 32 + n];
        float Cv  = dbc[bl * 64 + 48 + n];
        float dA  = __expf(dtv * Av);
        h = dA * h + dtv * Bv * xsv;
        float p = h * Cv;
        p += __shfl_xor(p, 1, 16);
        p += __shfl_xor(p, 2, 16);
        p += __shfl_xor(p, 4, 16);
        p += __shfl_xor(p, 8, 16);
        if (n == 0) {
            float y = p + Dv * xsv;
            float zv = xz[((size_t)bl << 10) + 512 + d];
            y *= zv / (1.f + expf(-zv));
            ym[bl * 512 + d] = y;
        }
    }
}

extern "C" void kernel_launch(void* const* d_in, const int* in_sizes, int n_in,
                              void* d_out, int out_size, void* d_ws, size_t ws_size,
                              hipStream_t stream)
{
    const float* x = (const float*)d_in[0];
    float* out = (float*)d_out;

    // workspace layout (floats)
    float* ws  = (float*)d_ws;
    float* xz  = ws;                       // M_*1024  (16MB)
    float* xs  = xz + (size_t)M_ * 1024;   // M_*512   (8MB)
    float* dbc = xs + (size_t)M_ * 512;    // M_*64    (1MB)
    float* dt  = dbc + (size_t)M_ * 64;    // M_*512   (8MB)
    float* ym  = dt + (size_t)M_ * 512;    // M_*512   (8MB)

    for (int dir = 0; dir < 2; dir++) {
        int wb = dir ? 10 : 1;
        const float* W_in    = (const float*)d_in[wb + 0];
        const float* W_conv  = (const float*)d_in[wb + 1];
        const float* b_conv  = (const float*)d_in[wb + 2];
        const float* W_xproj = (const float*)d_in[wb + 3];
        const float* W_dt    = (const float*)d_in[wb + 4];
        const float* b_dt    = (const float*)d_in[wb + 5];
        const float* A_log   = (const float*)d_in[wb + 6];
        const float* Dp      = (const float*)d_in[wb + 7];
        const float* W_out   = (const float*)d_in[wb + 8];

        // 1. xz = x @ W_in   (4096 x 1024)
        gemm_f32<<<dim3(1024 / 64, M_ / 64), 256, 0, stream>>>(x, W_in, xz, M_, 1024, 512, 0);
        // 2. conv + silu -> xs
        conv_silu<<<(M_ * 512) / 256, 256, 0, stream>>>(xz, W_conv, b_conv, xs, dir);
        // 3. dbc = xs @ W_xproj  (4096 x 64)
        gemm_f32<<<dim3(1, M_ / 64), 256, 0, stream>>>(xs, W_xproj, dbc, M_, 64, 512, 0);
        // 4. dt
        dt_kernel<<<(M_ * 512) / 256, 256, 0, stream>>>(dbc, W_dt, b_dt, dt);
        // 5. fused scan -> ym
        scan_kernel<<<(B_ * 512 * 16) / 256, 256, 0, stream>>>(dt, xs, dbc, xz, A_log, Dp, ym, dir);
        // 6. out (+)= ym @ W_out
        gemm_f32<<<dim3(512 / 64, M_ / 64), 256, 0, stream>>>(ym, W_out, out, M_, 512, 512, dir);
    }
}

// Round 2
// 765.031 us; speedup vs baseline: 2.7406x; 2.7406x over previous
//
#include <hip/hip_runtime.h>
#include <math.h>

// Bidirectional Mamba: B=4 L=1024 DM=DI=512 N=16 K=4 R=32, fp32.
// Backward dir uses anti-causal conv + reverse scan (no flips materialized).
// R2: chunked parallel scan — one block per (b,d), 16 chunks x 16 n-lanes,
//     in-block combine via LDS. 16x parallelism vs R1's sequential scan.

#define B_ 4
#define L_ 1024
#define DM_ 512
#define DI_ 512
#define NS_ 16
#define KC_ 4
#define RR_ 32
#define M_ (B_ * L_)   // 4096

// ---------------- generic tiled fp32 GEMM: C[M,N] = A[M,K] @ B[K,N] (+C if beta) ----
__global__ __launch_bounds__(256) void gemm_f32(
    const float* __restrict__ A, const float* __restrict__ Bm,
    float* __restrict__ C, int M, int N, int K, int beta)
{
    __shared__ float As[16][65];
    __shared__ float Bs[16][65];
    const int t = threadIdx.x;
    const int bm = blockIdx.y * 64;
    const int bn = blockIdx.x * 64;

    const int lr = t >> 2;          // 0..63  A row within tile
    const int lk = (t & 3) * 4;     // 0,4,8,12
    const int br = t >> 4;          // 0..15  B k-row
    const int bc = (t & 15) * 4;    // 0..60
    const int tm = (t >> 4) * 4;    // 0..60
    const int tn = (t & 15) * 4;

    float acc[4][4] = {};

    for (int k0 = 0; k0 < K; k0 += 16) {
        float4 av = *(const float4*)&A[(size_t)(bm + lr) * K + k0 + lk];
        float4 bv = *(const float4*)&Bm[(size_t)(k0 + br) * N + bn + bc];
        As[lk + 0][lr] = av.x;
        As[lk + 1][lr] = av.y;
        As[lk + 2][lr] = av.z;
        As[lk + 3][lr] = av.w;
        Bs[br][bc + 0] = bv.x;
        Bs[br][bc + 1] = bv.y;
        Bs[br][bc + 2] = bv.z;
        Bs[br][bc + 3] = bv.w;
        __syncthreads();
#pragma unroll
        for (int kk = 0; kk < 16; kk++) {
            float a0 = As[kk][tm + 0], a1 = As[kk][tm + 1];
            float a2 = As[kk][tm + 2], a3 = As[kk][tm + 3];
            float b0 = Bs[kk][tn + 0], b1 = Bs[kk][tn + 1];
            float b2 = Bs[kk][tn + 2], b3 = Bs[kk][tn + 3];
            acc[0][0] += a0 * b0; acc[0][1] += a0 * b1; acc[0][2] += a0 * b2; acc[0][3] += a0 * b3;
            acc[1][0] += a1 * b0; acc[1][1] += a1 * b1; acc[1][2] += a1 * b2; acc[1][3] += a1 * b3;
            acc[2][0] += a2 * b0; acc[2][1] += a2 * b1; acc[2][2] += a2 * b2; acc[2][3] += a2 * b3;
            acc[3][0] += a3 * b0; acc[3][1] += a3 * b1; acc[3][2] += a3 * b2; acc[3][3] += a3 * b3;
        }
        __syncthreads();
    }

#pragma unroll
    for (int i = 0; i < 4; i++) {
        float4* p = (float4*)&C[(size_t)(bm + tm + i) * N + bn + tn];
        float4 v = make_float4(acc[i][0], acc[i][1], acc[i][2], acc[i][3]);
        if (beta) {
            float4 o = *p;
            v.x += o.x; v.y += o.y; v.z += o.z; v.w += o.w;
        }
        *p = v;
    }
}

// ---------------- conv (causal fwd / anticausal bwd) + bias + SiLU -> xs ------------
__global__ __launch_bounds__(256) void conv_silu(
    const float* __restrict__ xz, const float* __restrict__ Wc,
    const float* __restrict__ bc, float* __restrict__ xs, int dir)
{
    int idx = blockIdx.x * 256 + threadIdx.x;       // over M_*512
    int d  = idx & 511;
    int bl = idx >> 9;
    int l  = bl & (L_ - 1);
    int b  = bl >> 10;

    float acc = bc[d];
    if (dir == 0) {
#pragma unroll
        for (int k = 0; k < KC_; k++) {
            int ls = l - 3 + k;
            if (ls >= 0) acc += xz[((size_t)(b * L_ + ls) << 10) + d] * Wc[d * 4 + k];
        }
    } else {
#pragma unroll
        for (int k = 0; k < KC_; k++) {
            int ls = l + 3 - k;
            if (ls < L_) acc += xz[((size_t)(b * L_ + ls) << 10) + d] * Wc[d * 4 + k];
        }
    }
    xs[idx] = acc / (1.f + expf(-acc));   // silu
}

// ---------------- dt = softplus(dt_in @ W_dt + b_dt) -------------------------------
__global__ __launch_bounds__(256) void dt_kernel(
    const float* __restrict__ dbc, const float* __restrict__ Wdt,
    const float* __restrict__ bdt, float* __restrict__ dt)
{
    int idx = blockIdx.x * 256 + threadIdx.x;  // over M_*512
    int d   = idx & 511;
    int row = idx >> 9;
    float acc = bdt[d];
#pragma unroll
    for (int k = 0; k < RR_; k++)
        acc += dbc[row * 64 + k] * Wdt[k * 512 + d];
    float sp = (acc > 20.f) ? acc : log1pf(expf(acc));
    dt[idx] = sp;
}

// ---------------- chunked selective scan + C-reduce + D skip + z-gate ---------------
// block = (b,d); threads: n = tid&15 (state dim), c = tid>>4 (chunk of 64 steps).
// Phase A: per-chunk (P = prod dA, S = local scan end) from h=0.
// Phase B: 16 threads combine chunk summaries -> chunk entry states H0.
// Phase C: rescan chunk from H0, reduce over n (shfl, width 16), write y.
__global__ __launch_bounds__(256) void scan_kernel(
    const float* __restrict__ dt, const float* __restrict__ xs,
    const float* __restrict__ dbc, const float* __restrict__ xz,
    const float* __restrict__ A_log, const float* __restrict__ Dp,
    float* __restrict__ ym, int dir)
{
    const int d = blockIdx.x & 511;
    const int b = blockIdx.x >> 9;
    const int tid = threadIdx.x;
    const int n = tid & 15;
    const int c = tid >> 4;          // 0..15
    const int Lc = L_ / 16;          // 64

    const float Av = -expf(A_log[d * 16 + n]);

    // Phase A: local scan from 0
    float P = 1.f, S = 0.f;
    for (int j = 0; j < Lc; j++) {
        int i = c * Lc + j;
        int l = dir ? (L_ - 1 - i) : i;
        int bl = b * L_ + l;
        float dtv = dt[bl * 512 + d];
        float xsv = xs[bl * 512 + d];
        float Bv  = dbc[bl * 64 + 32 + n];
        float dA  = __expf(dtv * Av);
        P *= dA;
        S = dA * S + dtv * Bv * xsv;
    }

    __shared__ float Ps[16][16];   // [c][n]
    __shared__ float Ss[16][16];
    __shared__ float H0[16][16];
    Ps[c][n] = P;
    Ss[c][n] = S;
    __syncthreads();

    // Phase B: serial combine over 16 chunk summaries (16 threads, one per n)
    if (tid < 16) {
        float h = 0.f;
#pragma unroll
        for (int cc = 0; cc < 16; cc++) {
            H0[cc][tid] = h;
            h = Ps[cc][tid] * h + Ss[cc][tid];
        }
    }
    __syncthreads();

    // Phase C: rescan from entry state, emit y
    float h = H0[c][n];
    const float Dv = Dp[d];
    for (int j = 0; j < Lc; j++) {
        int i = c * Lc + j;
        int l = dir ? (L_ - 1 - i) : i;
        int bl = b * L_ + l;
        float dtv = dt[bl * 512 + d];
        float xsv = xs[bl * 512 + d];
        float Bv  = dbc[bl * 64 + 32 + n];
        float Cv  = dbc[bl * 64 + 48 + n];
        float dA  = __expf(dtv * Av);
        h = dA * h + dtv * Bv * xsv;
        float p = h * Cv;
        p += __shfl_xor(p, 1, 16);
        p += __shfl_xor(p, 2, 16);
        p += __shfl_xor(p, 4, 16);
        p += __shfl_xor(p, 8, 16);
        if (n == 0) {
            float y = p + Dv * xsv;
            float zv = xz[((size_t)bl << 10) + 512 + d];
            y *= zv / (1.f + expf(-zv));
            ym[bl * 512 + d] = y;
        }
    }
}

extern "C" void kernel_launch(void* const* d_in, const int* in_sizes, int n_in,
                              void* d_out, int out_size, void* d_ws, size_t ws_size,
                              hipStream_t stream)
{
    const float* x = (const float*)d_in[0];
    float* out = (float*)d_out;

    // workspace layout (floats)
    float* ws  = (float*)d_ws;
    float* xz  = ws;                       // M_*1024  (16MB)
    float* xs  = xz + (size_t)M_ * 1024;   // M_*512   (8MB)
    float* dbc = xs + (size_t)M_ * 512;    // M_*64    (1MB)
    float* dt  = dbc + (size_t)M_ * 64;    // M_*512   (8MB)
    float* ym  = dt + (size_t)M_ * 512;    // M_*512   (8MB)

    for (int dir = 0; dir < 2; dir++) {
        int wb = dir ? 10 : 1;
        const float* W_in    = (const float*)d_in[wb + 0];
        const float* W_conv  = (const float*)d_in[wb + 1];
        const float* b_conv  = (const float*)d_in[wb + 2];
        const float* W_xproj = (const float*)d_in[wb + 3];
        const float* W_dt    = (const float*)d_in[wb + 4];
        const float* b_dt    = (const float*)d_in[wb + 5];
        const float* A_log   = (const float*)d_in[wb + 6];
        const float* Dp      = (const float*)d_in[wb + 7];
        const float* W_out   = (const float*)d_in[wb + 8];

        // 1. xz = x @ W_in   (4096 x 1024)
        gemm_f32<<<dim3(1024 / 64, M_ / 64), 256, 0, stream>>>(x, W_in, xz, M_, 1024, 512, 0);
        // 2. conv + silu -> xs
        conv_silu<<<(M_ * 512) / 256, 256, 0, stream>>>(xz, W_conv, b_conv, xs, dir);
        // 3. dbc = xs @ W_xproj  (4096 x 64)
        gemm_f32<<<dim3(1, M_ / 64), 256, 0, stream>>>(xs, W_xproj, dbc, M_, 64, 512, 0);
        // 4. dt
        dt_kernel<<<(M_ * 512) / 256, 256, 0, stream>>>(dbc, W_dt, b_dt, dt);
        // 5. chunked scan -> ym
        scan_kernel<<<B_ * 512, 256, 0, stream>>>(dt, xs, dbc, xz, A_log, Dp, ym, dir);
        // 6. out (+)= ym @ W_out
        gemm_f32<<<dim3(512 / 64, M_ / 64), 256, 0, stream>>>(ym, W_out, out, M_, 512, 512, dir);
    }
}

// Round 3
// 569.611 us; speedup vs baseline: 3.6808x; 1.3431x over previous
//
#include <hip/hip_runtime.h>
#include <hip/hip_bf16.h>
#include <math.h>

// Bidirectional Mamba: B=4 L=1024 DM=DI=512 N=16 K=4 R=32.
// R3: xz and out GEMMs -> bf16 MFMA (16x16x32, 128x128 tile, global_load_lds
//     16B staging, fragment-order LDS layout). xproj/dt/scan stay fp32.

#define B_ 4
#define L_ 1024
#define DM_ 512
#define DI_ 512
#define NS_ 16
#define KC_ 4
#define RR_ 32
#define M_ (B_ * L_)   // 4096

typedef short bf16x8 __attribute__((ext_vector_type(8)));
typedef float f32x4 __attribute__((ext_vector_type(4)));

__device__ inline void async_copy16(const void* g, void* l) {
    __builtin_amdgcn_global_load_lds((const __attribute__((address_space(1))) void*)g,
                                     (__attribute__((address_space(3))) void*)l, 16, 0, 0);
}

// ---------------- bf16 MFMA GEMM: C[M,N] (f32) = A[M,K] @ BT[N,K]  (+C if beta) -----
// A, BT bf16 row-major (stored as short). Tile 128x128, K-step 32, 4 waves/block,
// each wave computes a 64x64 quadrant as 4x4 MFMA 16x16x32 tiles.
// LDS tiles stored in fragment order: chunk16B index = kg*128 + row (kg = k/8).
__global__ __launch_bounds__(256) void gemm_bt_bf16(
    const short* __restrict__ A, const short* __restrict__ BT,
    float* __restrict__ C, int M, int N, int K, int beta)
{
    __shared__ alignas(16) short lds[8192];   // A: [0,4096), B: [4096,8192)
    short* lsA = lds;
    short* lsB = lds + 4096;

    const int tid  = threadIdx.x;
    const int lane = tid & 63;
    const int w    = tid >> 6;        // wave 0..3
    const int wm   = (w >> 1) * 64;   // quadrant m-offset
    const int wn   = (w & 1) * 64;    // quadrant n-offset
    const int m0   = blockIdx.y * 128;
    const int n0   = blockIdx.x * 128;

    const int lg = lane >> 4;         // k-group 0..3
    const int lr = lane & 15;         // row-in-tile 0..15

    f32x4 acc[4][4] = {};

    for (int k0 = 0; k0 < K; k0 += 32) {
        // stage A-tile and B-tile: 512 16B-chunks each; chunk c -> row=c&127, kg=c>>7
#pragma unroll
        for (int q = 0; q < 2; q++) {
            int ca = q * 256 + tid;                 // A chunk handled by this thread
            int ra = ca & 127, kga = ca >> 7;
            async_copy16(&A[(size_t)(m0 + ra) * K + k0 + kga * 8],
                         &lsA[(size_t)ca * 8 - lane * 8]);   // wave-uniform base + lane*16
            int cb = q * 256 + tid;
            int rb = cb & 127, kgb = cb >> 7;
            async_copy16(&BT[(size_t)(n0 + rb) * K + k0 + kgb * 8],
                         &lsB[(size_t)cb * 8 - lane * 8]);
        }
        __syncthreads();   // drains vmcnt before use

        bf16x8 af[4], bf[4];
#pragma unroll
        for (int mt = 0; mt < 4; mt++)
            af[mt] = *(const bf16x8*)&lsA[(lg * 128 + wm + mt * 16 + lr) * 8];
#pragma unroll
        for (int nt = 0; nt < 4; nt++)
            bf[nt] = *(const bf16x8*)&lsB[(lg * 128 + wn + nt * 16 + lr) * 8];
#pragma unroll
        for (int mt = 0; mt < 4; mt++)
#pragma unroll
            for (int nt = 0; nt < 4; nt++)
                acc[mt][nt] = __builtin_amdgcn_mfma_f32_16x16x32_bf16(
                    af[mt], bf[nt], acc[mt][nt], 0, 0, 0);
        __syncthreads();   // before overwriting LDS
    }

    // epilogue: C[m][n], m = wm + mt*16 + lg*4 + r, n = wn + nt*16 + lr
#pragma unroll
    for (int mt = 0; mt < 4; mt++) {
#pragma unroll
        for (int nt = 0; nt < 4; nt++) {
#pragma unroll
            for (int r = 0; r < 4; r++) {
                int m = m0 + wm + mt * 16 + lg * 4 + r;
                int n = n0 + wn + nt * 16 + lr;
                size_t idx = (size_t)m * N + n;
                float v = acc[mt][nt][r];
                if (beta) v += C[idx];
                C[idx] = v;
            }
        }
    }
}

// ---------------- cast fp32 -> bf16 ------------------------------------------------
__global__ __launch_bounds__(256) void cast_bf16(const float* __restrict__ src,
                                                 __hip_bfloat16* __restrict__ dst, int n)
{
    int i = blockIdx.x * 256 + threadIdx.x;
    if (i < n) dst[i] = __float2bfloat16(src[i]);
}

// ---------------- transpose-cast: W[K][N] f32 -> WT[N][K] bf16 ---------------------
__global__ __launch_bounds__(256) void transpose_cast(
    const float* __restrict__ W, __hip_bfloat16* __restrict__ WT, int K, int N)
{
    __shared__ float tile[32][33];
    int k0 = blockIdx.y * 32, n0 = blockIdx.x * 32;
    int tx = threadIdx.x & 31, ty = threadIdx.x >> 5;   // 32 x 8
#pragma unroll
    for (int i = 0; i < 4; i++)
        tile[ty + i * 8][tx] = W[(size_t)(k0 + ty + i * 8) * N + n0 + tx];
    __syncthreads();
#pragma unroll
    for (int i = 0; i < 4; i++)
        WT[(size_t)(n0 + ty + i * 8) * K + k0 + tx] =
            __float2bfloat16(tile[tx][ty + i * 8]);
}

// ---------------- generic tiled fp32 GEMM (kept for xproj: N=64) -------------------
__global__ __launch_bounds__(256) void gemm_f32(
    const float* __restrict__ A, const float* __restrict__ Bm,
    float* __restrict__ C, int M, int N, int K, int beta)
{
    __shared__ float As[16][65];
    __shared__ float Bs[16][65];
    const int t = threadIdx.x;
    const int bm = blockIdx.y * 64;
    const int bn = blockIdx.x * 64;

    const int lr = t >> 2;
    const int lk = (t & 3) * 4;
    const int br = t >> 4;
    const int bc = (t & 15) * 4;
    const int tm = (t >> 4) * 4;
    const int tn = (t & 15) * 4;

    float acc[4][4] = {};

    for (int k0 = 0; k0 < K; k0 += 16) {
        float4 av = *(const float4*)&A[(size_t)(bm + lr) * K + k0 + lk];
        float4 bv = *(const float4*)&Bm[(size_t)(k0 + br) * N + bn + bc];
        As[lk + 0][lr] = av.x;
        As[lk + 1][lr] = av.y;
        As[lk + 2][lr] = av.z;
        As[lk + 3][lr] = av.w;
        Bs[br][bc + 0] = bv.x;
        Bs[br][bc + 1] = bv.y;
        Bs[br][bc + 2] = bv.z;
        Bs[br][bc + 3] = bv.w;
        __syncthreads();
#pragma unroll
        for (int kk = 0; kk < 16; kk++) {
            float a0 = As[kk][tm + 0], a1 = As[kk][tm + 1];
            float a2 = As[kk][tm + 2], a3 = As[kk][tm + 3];
            float b0 = Bs[kk][tn + 0], b1 = Bs[kk][tn + 1];
            float b2 = Bs[kk][tn + 2], b3 = Bs[kk][tn + 3];
            acc[0][0] += a0 * b0; acc[0][1] += a0 * b1; acc[0][2] += a0 * b2; acc[0][3] += a0 * b3;
            acc[1][0] += a1 * b0; acc[1][1] += a1 * b1; acc[1][2] += a1 * b2; acc[1][3] += a1 * b3;
            acc[2][0] += a2 * b0; acc[2][1] += a2 * b1; acc[2][2] += a2 * b2; acc[2][3] += a2 * b3;
            acc[3][0] += a3 * b0; acc[3][1] += a3 * b1; acc[3][2] += a3 * b2; acc[3][3] += a3 * b3;
        }
        __syncthreads();
    }

#pragma unroll
    for (int i = 0; i < 4; i++) {
        float4* p = (float4*)&C[(size_t)(bm + tm + i) * N + bn + tn];
        float4 v = make_float4(acc[i][0], acc[i][1], acc[i][2], acc[i][3]);
        if (beta) {
            float4 o = *p;
            v.x += o.x; v.y += o.y; v.z += o.z; v.w += o.w;
        }
        *p = v;
    }
}

// ---------------- conv (causal fwd / anticausal bwd) + bias + SiLU -> xs (f32+bf16) -
__global__ __launch_bounds__(256) void conv_silu(
    const float* __restrict__ xz, const float* __restrict__ Wc,
    const float* __restrict__ bc, float* __restrict__ xs,
    __hip_bfloat16* __restrict__ xsb, int dir)
{
    int idx = blockIdx.x * 256 + threadIdx.x;
    int d  = idx & 511;
    int bl = idx >> 9;
    int l  = bl & (L_ - 1);
    int b  = bl >> 10;

    float acc = bc[d];
    if (dir == 0) {
#pragma unroll
        for (int k = 0; k < KC_; k++) {
            int ls = l - 3 + k;
            if (ls >= 0) acc += xz[((size_t)(b * L_ + ls) << 10) + d] * Wc[d * 4 + k];
        }
    } else {
#pragma unroll
        for (int k = 0; k < KC_; k++) {
            int ls = l + 3 - k;
            if (ls < L_) acc += xz[((size_t)(b * L_ + ls) << 10) + d] * Wc[d * 4 + k];
        }
    }
    float v = acc / (1.f + expf(-acc));
    xs[idx] = v;
    xsb[idx] = __float2bfloat16(v);
}

// ---------------- dt = softplus(dt_in @ W_dt + b_dt) -------------------------------
__global__ __launch_bounds__(256) void dt_kernel(
    const float* __restrict__ dbc, const float* __restrict__ Wdt,
    const float* __restrict__ bdt, float* __restrict__ dt)
{
    int idx = blockIdx.x * 256 + threadIdx.x;
    int d   = idx & 511;
    int row = idx >> 9;
    float acc = bdt[d];
#pragma unroll
    for (int k = 0; k < RR_; k++)
        acc += dbc[row * 64 + k] * Wdt[k * 512 + d];
    float sp = (acc > 20.f) ? acc : log1pf(expf(acc));
    dt[idx] = sp;
}

// ---------------- chunked selective scan + C-reduce + D skip + z-gate -> ym bf16 ----
__global__ __launch_bounds__(256) void scan_kernel(
    const float* __restrict__ dt, const float* __restrict__ xs,
    const float* __restrict__ dbc, const float* __restrict__ xz,
    const float* __restrict__ A_log, const float* __restrict__ Dp,
    __hip_bfloat16* __restrict__ ymb, int dir)
{
    const int d = blockIdx.x & 511;
    const int b = blockIdx.x >> 9;
    const int tid = threadIdx.x;
    const int n = tid & 15;
    const int c = tid >> 4;          // 0..15
    const int Lc = L_ / 16;          // 64

    const float Av = -expf(A_log[d * 16 + n]);

    float P = 1.f, S = 0.f;
    for (int j = 0; j < Lc; j++) {
        int i = c * Lc + j;
        int l = dir ? (L_ - 1 - i) : i;
        int bl = b * L_ + l;
        float dtv = dt[bl * 512 + d];
        float xsv = xs[bl * 512 + d];
        float Bv  = dbc[bl * 64 + 32 + n];
        float dA  = __expf(dtv * Av);
        P *= dA;
        S = dA * S + dtv * Bv * xsv;
    }

    __shared__ float Ps[16][16];
    __shared__ float Ss[16][16];
    __shared__ float H0[16][16];
    Ps[c][n] = P;
    Ss[c][n] = S;
    __syncthreads();

    if (tid < 16) {
        float h = 0.f;
#pragma unroll
        for (int cc = 0; cc < 16; cc++) {
            H0[cc][tid] = h;
            h = Ps[cc][tid] * h + Ss[cc][tid];
        }
    }
    __syncthreads();

    float h = H0[c][n];
    const float Dv = Dp[d];
    for (int j = 0; j < Lc; j++) {
        int i = c * Lc + j;
        int l = dir ? (L_ - 1 - i) : i;
        int bl = b * L_ + l;
        float dtv = dt[bl * 512 + d];
        float xsv = xs[bl * 512 + d];
        float Bv  = dbc[bl * 64 + 32 + n];
        float Cv  = dbc[bl * 64 + 48 + n];
        float dA  = __expf(dtv * Av);
        h = dA * h + dtv * Bv * xsv;
        float p = h * Cv;
        p += __shfl_xor(p, 1, 16);
        p += __shfl_xor(p, 2, 16);
        p += __shfl_xor(p, 4, 16);
        p += __shfl_xor(p, 8, 16);
        if (n == 0) {
            float y = p + Dv * xsv;
            float zv = xz[((size_t)bl << 10) + 512 + d];
            y *= zv / (1.f + expf(-zv));
            ymb[bl * 512 + d] = __float2bfloat16(y);
        }
    }
}

extern "C" void kernel_launch(void* const* d_in, const int* in_sizes, int n_in,
                              void* d_out, int out_size, void* d_ws, size_t ws_size,
                              hipStream_t stream)
{
    const float* x = (const float*)d_in[0];
    float* out = (float*)d_out;

    // workspace layout
    float* ws  = (float*)d_ws;
    float* xz  = ws;                        // M_*1024 f32   (16MB)
    float* xs  = xz + (size_t)M_ * 1024;    // M_*512  f32   (8MB)
    float* dbc = xs + (size_t)M_ * 512;     // M_*64   f32   (1MB)
    float* dt  = dbc + (size_t)M_ * 64;     // M_*512  f32   (8MB)
    __hip_bfloat16* xb   = (__hip_bfloat16*)(dt + (size_t)M_ * 512); // M_*512 bf16 (4MB)
    __hip_bfloat16* xsb  = xb  + (size_t)M_ * 512;   // M_*512 bf16 (4MB)
    __hip_bfloat16* ymb  = xsb + (size_t)M_ * 512;   // M_*512 bf16 (4MB)
    __hip_bfloat16* WinT = ymb + (size_t)M_ * 512;   // 1024*512 bf16 (1MB)
    __hip_bfloat16* WoutT= WinT + (size_t)1024 * 512;// 512*512 bf16 (0.5MB)

    // x -> bf16 once (shared by both directions)
    cast_bf16<<<(M_ * 512) / 256, 256, 0, stream>>>(x, xb, M_ * 512);

    for (int dir = 0; dir < 2; dir++) {
        int wb = dir ? 10 : 1;
        const float* W_in    = (const float*)d_in[wb + 0];
        const float* W_conv  = (const float*)d_in[wb + 1];
        const float* b_conv  = (const float*)d_in[wb + 2];
        const float* W_xproj = (const float*)d_in[wb + 3];
        const float* W_dt    = (const float*)d_in[wb + 4];
        const float* b_dt    = (const float*)d_in[wb + 5];
        const float* A_log   = (const float*)d_in[wb + 6];
        const float* Dp      = (const float*)d_in[wb + 7];
        const float* W_out   = (const float*)d_in[wb + 8];

        // weight transpose-casts
        transpose_cast<<<dim3(1024 / 32, 512 / 32), 256, 0, stream>>>(W_in, WinT, 512, 1024);
        transpose_cast<<<dim3(512 / 32, 512 / 32), 256, 0, stream>>>(W_out, WoutT, 512, 512);

        // 1. xz = x @ W_in   (bf16 MFMA)
        gemm_bt_bf16<<<dim3(1024 / 128, M_ / 128), 256, 0, stream>>>(
            (const short*)xb, (const short*)WinT, xz, M_, 1024, 512, 0);
        // 2. conv + silu -> xs (f32 + bf16)
        conv_silu<<<(M_ * 512) / 256, 256, 0, stream>>>(xz, W_conv, b_conv, xs, xsb, dir);
        // 3. dbc = xs @ W_xproj (fp32 — feeds sensitive dt path)
        gemm_f32<<<dim3(1, M_ / 64), 256, 0, stream>>>(xs, W_xproj, dbc, M_, 64, 512, 0);
        // 4. dt
        dt_kernel<<<(M_ * 512) / 256, 256, 0, stream>>>(dbc, W_dt, b_dt, dt);
        // 5. chunked scan -> ym (bf16)
        scan_kernel<<<B_ * 512, 256, 0, stream>>>(dt, xs, dbc, xz, A_log, Dp, ymb, dir);
        // 6. out (+)= ym @ W_out  (bf16 MFMA)
        gemm_bt_bf16<<<dim3(512 / 128, M_ / 128), 256, 0, stream>>>(
            (const short*)ymb, (const short*)WoutT, out, M_, 512, 512, dir);
    }
}

// Round 4
// 400.611 us; speedup vs baseline: 5.2336x; 1.4219x over previous
//
#include <hip/hip_runtime.h>
#include <hip/hip_bf16.h>
#include <math.h>

// Bidirectional Mamba: B=4 L=1024 DM=DI=512 N=16 K=4 R=32.
// R4: scan restructured — n(=16) in registers, threads along d (coalesced),
//     3 kernels: phaseA (chunk summaries), combine, phaseC (rescan+gate).
//     32 chunks x 32 steps. Removed dead xsb write; conv vectorized float4.

#define B_ 4
#define L_ 1024
#define DM_ 512
#define DI_ 512
#define NS_ 16
#define KC_ 4
#define RR_ 32
#define M_ (B_ * L_)   // 4096
#define CH_ 32         // chunks
#define CL_ 32         // steps per chunk

typedef short bf16x8 __attribute__((ext_vector_type(8)));
typedef float f32x4 __attribute__((ext_vector_type(4)));

__device__ inline void async_copy16(const void* g, void* l) {
    __builtin_amdgcn_global_load_lds((const __attribute__((address_space(1))) void*)g,
                                     (__attribute__((address_space(3))) void*)l, 16, 0, 0);
}

// ---------------- bf16 MFMA GEMM: C[M,N] (f32) = A[M,K] @ BT[N,K]  (+C if beta) -----
__global__ __launch_bounds__(256) void gemm_bt_bf16(
    const short* __restrict__ A, const short* __restrict__ BT,
    float* __restrict__ C, int M, int N, int K, int beta)
{
    __shared__ alignas(16) short lds[8192];
    short* lsA = lds;
    short* lsB = lds + 4096;

    const int tid  = threadIdx.x;
    const int lane = tid & 63;
    const int w    = tid >> 6;
    const int wm   = (w >> 1) * 64;
    const int wn   = (w & 1) * 64;
    const int m0   = blockIdx.y * 128;
    const int n0   = blockIdx.x * 128;

    const int lg = lane >> 4;
    const int lr = lane & 15;

    f32x4 acc[4][4] = {};

    for (int k0 = 0; k0 < K; k0 += 32) {
#pragma unroll
        for (int q = 0; q < 2; q++) {
            int ca = q * 256 + tid;
            int ra = ca & 127, kga = ca >> 7;
            async_copy16(&A[(size_t)(m0 + ra) * K + k0 + kga * 8],
                         &lsA[(size_t)ca * 8 - lane * 8]);
            int cb = q * 256 + tid;
            int rb = cb & 127, kgb = cb >> 7;
            async_copy16(&BT[(size_t)(n0 + rb) * K + k0 + kgb * 8],
                         &lsB[(size_t)cb * 8 - lane * 8]);
        }
        __syncthreads();

        bf16x8 af[4], bf[4];
#pragma unroll
        for (int mt = 0; mt < 4; mt++)
            af[mt] = *(const bf16x8*)&lsA[(lg * 128 + wm + mt * 16 + lr) * 8];
#pragma unroll
        for (int nt = 0; nt < 4; nt++)
            bf[nt] = *(const bf16x8*)&lsB[(lg * 128 + wn + nt * 16 + lr) * 8];
#pragma unroll
        for (int mt = 0; mt < 4; mt++)
#pragma unroll
            for (int nt = 0; nt < 4; nt++)
                acc[mt][nt] = __builtin_amdgcn_mfma_f32_16x16x32_bf16(
                    af[mt], bf[nt], acc[mt][nt], 0, 0, 0);
        __syncthreads();
    }

#pragma unroll
    for (int mt = 0; mt < 4; mt++) {
#pragma unroll
        for (int nt = 0; nt < 4; nt++) {
#pragma unroll
            for (int r = 0; r < 4; r++) {
                int m = m0 + wm + mt * 16 + lg * 4 + r;
                int n = n0 + wn + nt * 16 + lr;
                size_t idx = (size_t)m * N + n;
                float v = acc[mt][nt][r];
                if (beta) v += C[idx];
                C[idx] = v;
            }
        }
    }
}

// ---------------- cast fp32 -> bf16 ------------------------------------------------
__global__ __launch_bounds__(256) void cast_bf16(const float* __restrict__ src,
                                                 __hip_bfloat16* __restrict__ dst, int n)
{
    int i = blockIdx.x * 256 + threadIdx.x;
    if (i < n) dst[i] = __float2bfloat16(src[i]);
}

// ---------------- transpose-cast: W[K][N] f32 -> WT[N][K] bf16 ---------------------
__global__ __launch_bounds__(256) void transpose_cast(
    const float* __restrict__ W, __hip_bfloat16* __restrict__ WT, int K, int N)
{
    __shared__ float tile[32][33];
    int k0 = blockIdx.y * 32, n0 = blockIdx.x * 32;
    int tx = threadIdx.x & 31, ty = threadIdx.x >> 5;
#pragma unroll
    for (int i = 0; i < 4; i++)
        tile[ty + i * 8][tx] = W[(size_t)(k0 + ty + i * 8) * N + n0 + tx];
    __syncthreads();
#pragma unroll
    for (int i = 0; i < 4; i++)
        WT[(size_t)(n0 + ty + i * 8) * K + k0 + tx] =
            __float2bfloat16(tile[tx][ty + i * 8]);
}

// ---------------- generic tiled fp32 GEMM (xproj: N=64) ----------------------------
__global__ __launch_bounds__(256) void gemm_f32(
    const float* __restrict__ A, const float* __restrict__ Bm,
    float* __restrict__ C, int M, int N, int K, int beta)
{
    __shared__ float As[16][65];
    __shared__ float Bs[16][65];
    const int t = threadIdx.x;
    const int bm = blockIdx.y * 64;
    const int bn = blockIdx.x * 64;

    const int lr = t >> 2;
    const int lk = (t & 3) * 4;
    const int br = t >> 4;
    const int bc = (t & 15) * 4;
    const int tm = (t >> 4) * 4;
    const int tn = (t & 15) * 4;

    float acc[4][4] = {};

    for (int k0 = 0; k0 < K; k0 += 16) {
        float4 av = *(const float4*)&A[(size_t)(bm + lr) * K + k0 + lk];
        float4 bv = *(const float4*)&Bm[(size_t)(k0 + br) * N + bn + bc];
        As[lk + 0][lr] = av.x;
        As[lk + 1][lr] = av.y;
        As[lk + 2][lr] = av.z;
        As[lk + 3][lr] = av.w;
        Bs[br][bc + 0] = bv.x;
        Bs[br][bc + 1] = bv.y;
        Bs[br][bc + 2] = bv.z;
        Bs[br][bc + 3] = bv.w;
        __syncthreads();
#pragma unroll
        for (int kk = 0; kk < 16; kk++) {
            float a0 = As[kk][tm + 0], a1 = As[kk][tm + 1];
            float a2 = As[kk][tm + 2], a3 = As[kk][tm + 3];
            float b0 = Bs[kk][tn + 0], b1 = Bs[kk][tn + 1];
            float b2 = Bs[kk][tn + 2], b3 = Bs[kk][tn + 3];
            acc[0][0] += a0 * b0; acc[0][1] += a0 * b1; acc[0][2] += a0 * b2; acc[0][3] += a0 * b3;
            acc[1][0] += a1 * b0; acc[1][1] += a1 * b1; acc[1][2] += a1 * b2; acc[1][3] += a1 * b3;
            acc[2][0] += a2 * b0; acc[2][1] += a2 * b1; acc[2][2] += a2 * b2; acc[2][3] += a2 * b3;
            acc[3][0] += a3 * b0; acc[3][1] += a3 * b1; acc[3][2] += a3 * b2; acc[3][3] += a3 * b3;
        }
        __syncthreads();
    }

#pragma unroll
    for (int i = 0; i < 4; i++) {
        float4* p = (float4*)&C[(size_t)(bm + tm + i) * N + bn + tn];
        float4 v = make_float4(acc[i][0], acc[i][1], acc[i][2], acc[i][3]);
        if (beta) {
            float4 o = *p;
            v.x += o.x; v.y += o.y; v.z += o.z; v.w += o.w;
        }
        *p = v;
    }
}

// ---------------- conv (causal fwd / anticausal bwd) + bias + SiLU -> xs (float4) ---
__global__ __launch_bounds__(256) void conv_silu4(
    const float* __restrict__ xz, const float* __restrict__ Wc,
    const float* __restrict__ bc, float* __restrict__ xs, int dir)
{
    int idx = blockIdx.x * 256 + threadIdx.x;     // over M_*128
    int d4 = (idx & 127) * 4;
    int bl = idx >> 7;
    int l  = bl & (L_ - 1);
    int b  = bl >> 10;

    float4 acc = *(const float4*)&bc[d4];
    float wA[4][4];
#pragma unroll
    for (int i = 0; i < 4; i++) {
        float4 t = *(const float4*)&Wc[(d4 + i) * 4];
        wA[i][0] = t.x; wA[i][1] = t.y; wA[i][2] = t.z; wA[i][3] = t.w;
    }
#pragma unroll
    for (int k = 0; k < KC_; k++) {
        int ls = dir ? (l + 3 - k) : (l - 3 + k);
        if (ls >= 0 && ls < L_) {
            float4 xv = *(const float4*)&xz[((size_t)(b * L_ + ls)) * 1024 + d4];
            acc.x += xv.x * wA[0][k];
            acc.y += xv.y * wA[1][k];
            acc.z += xv.z * wA[2][k];
            acc.w += xv.w * wA[3][k];
        }
    }
    float4 o;
    o.x = acc.x / (1.f + __expf(-acc.x));
    o.y = acc.y / (1.f + __expf(-acc.y));
    o.z = acc.z / (1.f + __expf(-acc.z));
    o.w = acc.w / (1.f + __expf(-acc.w));
    *(float4*)&xs[(size_t)bl * 512 + d4] = o;
}

// ---------------- dt = softplus(dt_in @ W_dt + b_dt) -------------------------------
__global__ __launch_bounds__(256) void dt_kernel(
    const float* __restrict__ dbc, const float* __restrict__ Wdt,
    const float* __restrict__ bdt, float* __restrict__ dt)
{
    int idx = blockIdx.x * 256 + threadIdx.x;
    int d   = idx & 511;
    int row = idx >> 9;
    float acc = bdt[d];
#pragma unroll
    for (int k = 0; k < RR_; k++)
        acc += dbc[row * 64 + k] * Wdt[k * 512 + d];
    float sp = (acc > 20.f) ? acc : log1pf(expf(acc));
    dt[idx] = sp;
}

// ---------------- scan phase A: per-chunk summaries --------------------------------
// grid (2, CH_, B_), block 256: thread = d = bx*256+tid; 16 n-states in registers.
// Emits sdt (sum of dt over chunk) and S[16] (local scan from h=0).
__global__ __launch_bounds__(256) void scan_phaseA(
    const float* __restrict__ dt, const float* __restrict__ xs,
    const float* __restrict__ dbc, const float* __restrict__ A_log,
    float* __restrict__ sdtb, float* __restrict__ Sb, int dir)
{
    const int tid = threadIdx.x;
    const int d = blockIdx.x * 256 + tid;
    const int c = blockIdx.y;
    const int b = blockIdx.z;

    __shared__ float Bs[CL_][16];
    {
        int j = tid >> 3, n2 = (tid & 7) * 2;
        int i = c * CL_ + j;
        int l = dir ? (L_ - 1 - i) : i;
        const float2 v = *(const float2*)&dbc[((size_t)(b * L_ + l)) * 64 + 32 + n2];
        Bs[j][n2] = v.x; Bs[j][n2 + 1] = v.y;
    }
    __syncthreads();

    float Av[16];
    {
        const float4* ap = (const float4*)&A_log[d * 16];
#pragma unroll
        for (int q = 0; q < 4; q++) {
            float4 a = ap[q];
            Av[q * 4 + 0] = -__expf(a.x);
            Av[q * 4 + 1] = -__expf(a.y);
            Av[q * 4 + 2] = -__expf(a.z);
            Av[q * 4 + 3] = -__expf(a.w);
        }
    }

    const int i0 = c * CL_;
    const int l0 = dir ? (L_ - 1 - i0) : i0;
    const int stepE = dir ? -512 : 512;
    const float* pdt = dt + ((size_t)(b * L_ + l0)) * 512 + d;
    const float* pxs = xs + ((size_t)(b * L_ + l0)) * 512 + d;

    float h[16];
#pragma unroll
    for (int n = 0; n < 16; n++) h[n] = 0.f;
    float sdt = 0.f;

    for (int half = 0; half < 2; half++) {
        float dbuf[16], xbuf[16];
#pragma unroll
        for (int j = 0; j < 16; j++) {
            int jj = half * 16 + j;
            dbuf[j] = pdt[jj * stepE];
            xbuf[j] = pxs[jj * stepE];
        }
#pragma unroll
        for (int j = 0; j < 16; j++) {
            int jj = half * 16 + j;
            float dtv = dbuf[j], xsv = xbuf[j];
            float u = dtv * xsv;
            sdt += dtv;
#pragma unroll
            for (int n = 0; n < 16; n++)
                h[n] = __expf(dtv * Av[n]) * h[n] + u * Bs[jj][n];
        }
    }

    size_t base = (size_t)(b * CH_ + c) * 512 + d;
    sdtb[base] = sdt;
    float4* Sp = (float4*)&Sb[base * 16];
#pragma unroll
    for (int q = 0; q < 4; q++)
        Sp[q] = make_float4(h[q * 4], h[q * 4 + 1], h[q * 4 + 2], h[q * 4 + 3]);
}

// ---------------- scan combine: chunk entry states ---------------------------------
__global__ __launch_bounds__(256) void scan_combine(
    const float* __restrict__ sdtb, const float* __restrict__ Sb,
    const float* __restrict__ A_log, float* __restrict__ H0b)
{
    int t = blockIdx.x * 256 + threadIdx.x;   // 32768 = B_*512*16
    int n = t & 15;
    int d = (t >> 4) & 511;
    int b = t >> 13;
    float Av = -expf(A_log[d * 16 + n]);
    float h = 0.f;
    for (int c = 0; c < CH_; c++) {
        size_t base = (size_t)(b * CH_ + c) * 512 + d;
        H0b[base * 16 + n] = h;
        h = __expf(Av * sdtb[base]) * h + Sb[base * 16 + n];
    }
}

// ---------------- scan phase C: rescan + C-dot + D-skip + z-gate -> ym bf16 ---------
__global__ __launch_bounds__(256) void scan_phaseC(
    const float* __restrict__ dt, const float* __restrict__ xs,
    const float* __restrict__ dbc, const float* __restrict__ xz,
    const float* __restrict__ A_log, const float* __restrict__ Dp,
    const float* __restrict__ H0b, __hip_bfloat16* __restrict__ ymb, int dir)
{
    const int tid = threadIdx.x;
    const int d = blockIdx.x * 256 + tid;
    const int c = blockIdx.y;
    const int b = blockIdx.z;

    __shared__ float Ls[CL_][32];   // [j][0:16)=B, [j][16:32)=C
    {
        int j = tid >> 3, q = (tid & 7) * 4;
        int i = c * CL_ + j;
        int l = dir ? (L_ - 1 - i) : i;
        const float4 v = *(const float4*)&dbc[((size_t)(b * L_ + l)) * 64 + 32 + q];
        Ls[j][q] = v.x; Ls[j][q + 1] = v.y; Ls[j][q + 2] = v.z; Ls[j][q + 3] = v.w;
    }
    __syncthreads();

    float Av[16];
    {
        const float4* ap = (const float4*)&A_log[d * 16];
#pragma unroll
        for (int q = 0; q < 4; q++) {
            float4 a = ap[q];
            Av[q * 4 + 0] = -__expf(a.x);
            Av[q * 4 + 1] = -__expf(a.y);
            Av[q * 4 + 2] = -__expf(a.z);
            Av[q * 4 + 3] = -__expf(a.w);
        }
    }

    float h[16];
    {
        size_t base = (size_t)(b * CH_ + c) * 512 + d;
        const float4* Hp = (const float4*)&H0b[base * 16];
#pragma unroll
        for (int q = 0; q < 4; q++) {
            float4 v = Hp[q];
            h[q * 4 + 0] = v.x; h[q * 4 + 1] = v.y; h[q * 4 + 2] = v.z; h[q * 4 + 3] = v.w;
        }
    }
    const float Dv = Dp[d];

    const int i0 = c * CL_;
    const int l0 = dir ? (L_ - 1 - i0) : i0;
    const int stepE = dir ? -512 : 512;
    const int stepZ = dir ? -1024 : 1024;
    const float* pdt = dt + ((size_t)(b * L_ + l0)) * 512 + d;
    const float* pxs = xs + ((size_t)(b * L_ + l0)) * 512 + d;
    const float* pz  = xz + ((size_t)(b * L_ + l0)) * 1024 + 512 + d;
    __hip_bfloat16* pym = ymb + ((size_t)(b * L_ + l0)) * 512 + d;

    for (int half = 0; half < 2; half++) {
        float dbuf[16], xbuf[16], zbuf[16];
#pragma unroll
        for (int j = 0; j < 16; j++) {
            int jj = half * 16 + j;
            dbuf[j] = pdt[jj * stepE];
            xbuf[j] = pxs[jj * stepE];
            zbuf[j] = pz[jj * stepZ];
        }
#pragma unroll
        for (int j = 0; j < 16; j++) {
            int jj = half * 16 + j;
            float dtv = dbuf[j], xsv = xbuf[j];
            float u = dtv * xsv;
            float dot = 0.f;
#pragma unroll
            for (int n = 0; n < 16; n++) {
                h[n] = __expf(dtv * Av[n]) * h[n] + u * Ls[jj][n];
                dot += h[n] * Ls[jj][16 + n];
            }
            float y = dot + Dv * xsv;
            float zv = zbuf[j];
            y *= zv / (1.f + __expf(-zv));
            pym[jj * stepE] = __float2bfloat16(y);
        }
    }
}

extern "C" void kernel_launch(void* const* d_in, const int* in_sizes, int n_in,
                              void* d_out, int out_size, void* d_ws, size_t ws_size,
                              hipStream_t stream)
{
    const float* x = (const float*)d_in[0];
    float* out = (float*)d_out;

    // workspace layout
    float* ws  = (float*)d_ws;
    float* xz  = ws;                        // M_*1024 f32  (16MB)
    float* xs  = xz + (size_t)M_ * 1024;    // M_*512  f32  (8MB)
    float* dbc = xs + (size_t)M_ * 512;     // M_*64   f32  (1MB)
    float* dt  = dbc + (size_t)M_ * 64;     // M_*512  f32  (8MB)
    __hip_bfloat16* xb   = (__hip_bfloat16*)(dt + (size_t)M_ * 512); // M_*512 bf16
    __hip_bfloat16* ymb  = xb  + (size_t)M_ * 512;    // M_*512 bf16
    __hip_bfloat16* WinT = ymb + (size_t)M_ * 512;    // 1024*512 bf16
    __hip_bfloat16* WoutT= WinT + (size_t)1024 * 512; // 512*512 bf16
    float* sdtb = (float*)(WoutT + (size_t)512 * 512);        // B*CH*512      (0.25MB)
    float* Sb   = sdtb + (size_t)B_ * CH_ * 512;              // B*CH*512*16   (4MB)
    float* H0b  = Sb + (size_t)B_ * CH_ * 512 * 16;           // B*CH*512*16   (4MB)

    // x -> bf16 once (shared by both directions)
    cast_bf16<<<(M_ * 512) / 256, 256, 0, stream>>>(x, xb, M_ * 512);

    for (int dir = 0; dir < 2; dir++) {
        int wb = dir ? 10 : 1;
        const float* W_in    = (const float*)d_in[wb + 0];
        const float* W_conv  = (const float*)d_in[wb + 1];
        const float* b_conv  = (const float*)d_in[wb + 2];
        const float* W_xproj = (const float*)d_in[wb + 3];
        const float* W_dt    = (const float*)d_in[wb + 4];
        const float* b_dt    = (const float*)d_in[wb + 5];
        const float* A_log   = (const float*)d_in[wb + 6];
        const float* Dp      = (const float*)d_in[wb + 7];
        const float* W_out   = (const float*)d_in[wb + 8];

        transpose_cast<<<dim3(1024 / 32, 512 / 32), 256, 0, stream>>>(W_in, WinT, 512, 1024);
        transpose_cast<<<dim3(512 / 32, 512 / 32), 256, 0, stream>>>(W_out, WoutT, 512, 512);

        // 1. xz = x @ W_in   (bf16 MFMA)
        gemm_bt_bf16<<<dim3(1024 / 128, M_ / 128), 256, 0, stream>>>(
            (const short*)xb, (const short*)WinT, xz, M_, 1024, 512, 0);
        // 2. conv + silu -> xs
        conv_silu4<<<(M_ * 128) / 256, 256, 0, stream>>>(xz, W_conv, b_conv, xs, dir);
        // 3. dbc = xs @ W_xproj (fp32 — feeds sensitive dt path)
        gemm_f32<<<dim3(1, M_ / 64), 256, 0, stream>>>(xs, W_xproj, dbc, M_, 64, 512, 0);
        // 4. dt
        dt_kernel<<<(M_ * 512) / 256, 256, 0, stream>>>(dbc, W_dt, b_dt, dt);
        // 5. scan: phaseA -> combine -> phaseC
        scan_phaseA<<<dim3(2, CH_, B_), 256, 0, stream>>>(dt, xs, dbc, A_log, sdtb, Sb, dir);
        scan_combine<<<(B_ * 512 * 16) / 256, 256, 0, stream>>>(sdtb, Sb, A_log, H0b);
        scan_phaseC<<<dim3(2, CH_, B_), 256, 0, stream>>>(dt, xs, dbc, xz, A_log, Dp, H0b, ymb, dir);
        // 6. out (+)= ym @ W_out  (bf16 MFMA)
        gemm_bt_bf16<<<dim3(512 / 128, M_ / 128), 256, 0, stream>>>(
            (const short*)ymb, (const short*)WoutT, out, M_, 512, 512, dir);
    }
}

// Round 5
// 347.302 us; speedup vs baseline: 6.0370x; 1.1535x over previous
//
#include <hip/hip_runtime.h>
#include <hip/hip_bf16.h>
#include <math.h>

// Bidirectional Mamba: B=4 L=1024 DM=DI=512 N=16 K=4 R=32.
// R5: xproj GEMM (N=64) -> shape-specialized kernel, 16 rows x 64 cols per block
//     (256 blocks vs 64 — kills the 2.5%-occupancy latency stall + bank conflicts).
//     dt kernel vectorized float4.

#define B_ 4
#define L_ 1024
#define DM_ 512
#define DI_ 512
#define NS_ 16
#define KC_ 4
#define RR_ 32
#define M_ (B_ * L_)   // 4096
#define CH_ 32         // scan chunks
#define CL_ 32         // steps per chunk

typedef short bf16x8 __attribute__((ext_vector_type(8)));
typedef float f32x4 __attribute__((ext_vector_type(4)));

__device__ inline void async_copy16(const void* g, void* l) {
    __builtin_amdgcn_global_load_lds((const __attribute__((address_space(1))) void*)g,
                                     (__attribute__((address_space(3))) void*)l, 16, 0, 0);
}

// ---------------- bf16 MFMA GEMM: C[M,N] (f32) = A[M,K] @ BT[N,K]  (+C if beta) -----
__global__ __launch_bounds__(256) void gemm_bt_bf16(
    const short* __restrict__ A, const short* __restrict__ BT,
    float* __restrict__ C, int M, int N, int K, int beta)
{
    __shared__ alignas(16) short lds[8192];
    short* lsA = lds;
    short* lsB = lds + 4096;

    const int tid  = threadIdx.x;
    const int lane = tid & 63;
    const int w    = tid >> 6;
    const int wm   = (w >> 1) * 64;
    const int wn   = (w & 1) * 64;
    const int m0   = blockIdx.y * 128;
    const int n0   = blockIdx.x * 128;

    const int lg = lane >> 4;
    const int lr = lane & 15;

    f32x4 acc[4][4] = {};

    for (int k0 = 0; k0 < K; k0 += 32) {
#pragma unroll
        for (int q = 0; q < 2; q++) {
            int ca = q * 256 + tid;
            int ra = ca & 127, kga = ca >> 7;
            async_copy16(&A[(size_t)(m0 + ra) * K + k0 + kga * 8],
                         &lsA[(size_t)ca * 8 - lane * 8]);
            int cb = q * 256 + tid;
            int rb = cb & 127, kgb = cb >> 7;
            async_copy16(&BT[(size_t)(n0 + rb) * K + k0 + kgb * 8],
                         &lsB[(size_t)cb * 8 - lane * 8]);
        }
        __syncthreads();

        bf16x8 af[4], bf[4];
#pragma unroll
        for (int mt = 0; mt < 4; mt++)
            af[mt] = *(const bf16x8*)&lsA[(lg * 128 + wm + mt * 16 + lr) * 8];
#pragma unroll
        for (int nt = 0; nt < 4; nt++)
            bf[nt] = *(const bf16x8*)&lsB[(lg * 128 + wn + nt * 16 + lr) * 8];
#pragma unroll
        for (int mt = 0; mt < 4; mt++)
#pragma unroll
            for (int nt = 0; nt < 4; nt++)
                acc[mt][nt] = __builtin_amdgcn_mfma_f32_16x16x32_bf16(
                    af[mt], bf[nt], acc[mt][nt], 0, 0, 0);
        __syncthreads();
    }

#pragma unroll
    for (int mt = 0; mt < 4; mt++) {
#pragma unroll
        for (int nt = 0; nt < 4; nt++) {
#pragma unroll
            for (int r = 0; r < 4; r++) {
                int m = m0 + wm + mt * 16 + lg * 4 + r;
                int n = n0 + wn + nt * 16 + lr;
                size_t idx = (size_t)m * N + n;
                float v = acc[mt][nt][r];
                if (beta) v += C[idx];
                C[idx] = v;
            }
        }
    }
}

// ---------------- cast fp32 -> bf16 ------------------------------------------------
__global__ __launch_bounds__(256) void cast_bf16(const float* __restrict__ src,
                                                 __hip_bfloat16* __restrict__ dst, int n)
{
    int i = blockIdx.x * 256 + threadIdx.x;
    if (i < n) dst[i] = __float2bfloat16(src[i]);
}

// ---------------- transpose-cast: W[K][N] f32 -> WT[N][K] bf16 ---------------------
__global__ __launch_bounds__(256) void transpose_cast(
    const float* __restrict__ W, __hip_bfloat16* __restrict__ WT, int K, int N)
{
    __shared__ float tile[32][33];
    int k0 = blockIdx.y * 32, n0 = blockIdx.x * 32;
    int tx = threadIdx.x & 31, ty = threadIdx.x >> 5;
#pragma unroll
    for (int i = 0; i < 4; i++)
        tile[ty + i * 8][tx] = W[(size_t)(k0 + ty + i * 8) * N + n0 + tx];
    __syncthreads();
#pragma unroll
    for (int i = 0; i < 4; i++)
        WT[(size_t)(n0 + ty + i * 8) * K + k0 + tx] =
            __float2bfloat16(tile[tx][ty + i * 8]);
}

// ---------------- xproj: dbc[M,64] = xs[M,512] @ Wx[512,64] ------------------------
// 16 rows x 64 cols per block, 256 blocks. K chunked by 64.
// Ws reads: 16 b128 spanning 64 floats -> 2-way bank alias (free).
// As reads: 16-lane broadcast (conflict-free).
__global__ __launch_bounds__(256) void xproj_gemm(
    const float* __restrict__ A, const float* __restrict__ W,
    float* __restrict__ Cc)
{
    __shared__ float Ws[64][64];   // [kk][n] 16KB
    __shared__ float As[16][64];   // [r][kk]  4KB
    const int t = threadIdx.x;
    const int row0 = blockIdx.x * 16;
    const int r  = t >> 4;
    const int n4 = (t & 15) * 4;

    float4 acc = make_float4(0.f, 0.f, 0.f, 0.f);

    for (int k0 = 0; k0 < 512; k0 += 64) {
#pragma unroll
        for (int i = 0; i < 4; i++) {
            int f = t + 256 * i;                    // float4 slot: kk = f>>4, ng = f&15
            *(float4*)&Ws[f >> 4][(f & 15) * 4] =
                *(const float4*)&W[(size_t)(k0 + (f >> 4)) * 64 + (f & 15) * 4];
        }
        *(float4*)&As[t >> 4][(t & 15) * 4] =
            *(const float4*)&A[(size_t)(row0 + (t >> 4)) * 512 + k0 + (t & 15) * 4];
        __syncthreads();

#pragma unroll
        for (int kk4 = 0; kk4 < 16; kk4++) {
            float4 av = *(const float4*)&As[r][kk4 * 4];
            float4 w0 = *(const float4*)&Ws[kk4 * 4 + 0][n4];
            acc.x += av.x * w0.x; acc.y += av.x * w0.y; acc.z += av.x * w0.z; acc.w += av.x * w0.w;
            float4 w1 = *(const float4*)&Ws[kk4 * 4 + 1][n4];
            acc.x += av.y * w1.x; acc.y += av.y * w1.y; acc.z += av.y * w1.z; acc.w += av.y * w1.w;
            float4 w2 = *(const float4*)&Ws[kk4 * 4 + 2][n4];
            acc.x += av.z * w2.x; acc.y += av.z * w2.y; acc.z += av.z * w2.z; acc.w += av.z * w2.w;
            float4 w3 = *(const float4*)&Ws[kk4 * 4 + 3][n4];
            acc.x += av.w * w3.x; acc.y += av.w * w3.y; acc.z += av.w * w3.z; acc.w += av.w * w3.w;
        }
        __syncthreads();
    }

    *(float4*)&Cc[(size_t)(row0 + r) * 64 + n4] = acc;
}

// ---------------- conv (causal fwd / anticausal bwd) + bias + SiLU -> xs (float4) ---
__global__ __launch_bounds__(256) void conv_silu4(
    const float* __restrict__ xz, const float* __restrict__ Wc,
    const float* __restrict__ bc, float* __restrict__ xs, int dir)
{
    int idx = blockIdx.x * 256 + threadIdx.x;     // over M_*128
    int d4 = (idx & 127) * 4;
    int bl = idx >> 7;
    int l  = bl & (L_ - 1);
    int b  = bl >> 10;

    float4 acc = *(const float4*)&bc[d4];
    float wA[4][4];
#pragma unroll
    for (int i = 0; i < 4; i++) {
        float4 t = *(const float4*)&Wc[(d4 + i) * 4];
        wA[i][0] = t.x; wA[i][1] = t.y; wA[i][2] = t.z; wA[i][3] = t.w;
    }
#pragma unroll
    for (int k = 0; k < KC_; k++) {
        int ls = dir ? (l + 3 - k) : (l - 3 + k);
        if (ls >= 0 && ls < L_) {
            float4 xv = *(const float4*)&xz[((size_t)(b * L_ + ls)) * 1024 + d4];
            acc.x += xv.x * wA[0][k];
            acc.y += xv.y * wA[1][k];
            acc.z += xv.z * wA[2][k];
            acc.w += xv.w * wA[3][k];
        }
    }
    float4 o;
    o.x = acc.x / (1.f + __expf(-acc.x));
    o.y = acc.y / (1.f + __expf(-acc.y));
    o.z = acc.z / (1.f + __expf(-acc.z));
    o.w = acc.w / (1.f + __expf(-acc.w));
    *(float4*)&xs[(size_t)bl * 512 + d4] = o;
}

// ---------------- dt = softplus(dt_in @ W_dt + b_dt), float4 -----------------------
__global__ __launch_bounds__(256) void dt_kernel4(
    const float* __restrict__ dbc, const float* __restrict__ Wdt,
    const float* __restrict__ bdt, float* __restrict__ dt)
{
    int idx = blockIdx.x * 256 + threadIdx.x;   // over M_*128
    int d4  = (idx & 127) * 4;
    int row = idx >> 7;
    float4 acc = *(const float4*)&bdt[d4];
    const float* dr = &dbc[(size_t)row * 64];
#pragma unroll
    for (int k = 0; k < RR_; k += 4) {
        float4 dv = *(const float4*)&dr[k];
        float4 w0 = *(const float4*)&Wdt[(size_t)(k + 0) * 512 + d4];
        acc.x += dv.x * w0.x; acc.y += dv.x * w0.y; acc.z += dv.x * w0.z; acc.w += dv.x * w0.w;
        float4 w1 = *(const float4*)&Wdt[(size_t)(k + 1) * 512 + d4];
        acc.x += dv.y * w1.x; acc.y += dv.y * w1.y; acc.z += dv.y * w1.z; acc.w += dv.y * w1.w;
        float4 w2 = *(const float4*)&Wdt[(size_t)(k + 2) * 512 + d4];
        acc.x += dv.z * w2.x; acc.y += dv.z * w2.y; acc.z += dv.z * w2.z; acc.w += dv.z * w2.w;
        float4 w3 = *(const float4*)&Wdt[(size_t)(k + 3) * 512 + d4];
        acc.x += dv.w * w3.x; acc.y += dv.w * w3.y; acc.z += dv.w * w3.z; acc.w += dv.w * w3.w;
    }
    float4 o;
    o.x = (acc.x > 20.f) ? acc.x : log1pf(expf(acc.x));
    o.y = (acc.y > 20.f) ? acc.y : log1pf(expf(acc.y));
    o.z = (acc.z > 20.f) ? acc.z : log1pf(expf(acc.z));
    o.w = (acc.w > 20.f) ? acc.w : log1pf(expf(acc.w));
    *(float4*)&dt[(size_t)row * 512 + d4] = o;
}

// ---------------- scan phase A: per-chunk summaries --------------------------------
__global__ __launch_bounds__(256) void scan_phaseA(
    const float* __restrict__ dt, const float* __restrict__ xs,
    const float* __restrict__ dbc, const float* __restrict__ A_log,
    float* __restrict__ sdtb, float* __restrict__ Sb, int dir)
{
    const int tid = threadIdx.x;
    const int d = blockIdx.x * 256 + tid;
    const int c = blockIdx.y;
    const int b = blockIdx.z;

    __shared__ float Bs[CL_][16];
    {
        int j = tid >> 3, n2 = (tid & 7) * 2;
        int i = c * CL_ + j;
        int l = dir ? (L_ - 1 - i) : i;
        const float2 v = *(const float2*)&dbc[((size_t)(b * L_ + l)) * 64 + 32 + n2];
        Bs[j][n2] = v.x; Bs[j][n2 + 1] = v.y;
    }
    __syncthreads();

    float Av[16];
    {
        const float4* ap = (const float4*)&A_log[d * 16];
#pragma unroll
        for (int q = 0; q < 4; q++) {
            float4 a = ap[q];
            Av[q * 4 + 0] = -__expf(a.x);
            Av[q * 4 + 1] = -__expf(a.y);
            Av[q * 4 + 2] = -__expf(a.z);
            Av[q * 4 + 3] = -__expf(a.w);
        }
    }

    const int i0 = c * CL_;
    const int l0 = dir ? (L_ - 1 - i0) : i0;
    const int stepE = dir ? -512 : 512;
    const float* pdt = dt + ((size_t)(b * L_ + l0)) * 512 + d;
    const float* pxs = xs + ((size_t)(b * L_ + l0)) * 512 + d;

    float h[16];
#pragma unroll
    for (int n = 0; n < 16; n++) h[n] = 0.f;
    float sdt = 0.f;

    for (int half = 0; half < 2; half++) {
        float dbuf[16], xbuf[16];
#pragma unroll
        for (int j = 0; j < 16; j++) {
            int jj = half * 16 + j;
            dbuf[j] = pdt[jj * stepE];
            xbuf[j] = pxs[jj * stepE];
        }
#pragma unroll
        for (int j = 0; j < 16; j++) {
            int jj = half * 16 + j;
            float dtv = dbuf[j], xsv = xbuf[j];
            float u = dtv * xsv;
            sdt += dtv;
#pragma unroll
            for (int n = 0; n < 16; n++)
                h[n] = __expf(dtv * Av[n]) * h[n] + u * Bs[jj][n];
        }
    }

    size_t base = (size_t)(b * CH_ + c) * 512 + d;
    sdtb[base] = sdt;
    float4* Sp = (float4*)&Sb[base * 16];
#pragma unroll
    for (int q = 0; q < 4; q++)
        Sp[q] = make_float4(h[q * 4], h[q * 4 + 1], h[q * 4 + 2], h[q * 4 + 3]);
}

// ---------------- scan combine: chunk entry states ---------------------------------
__global__ __launch_bounds__(256) void scan_combine(
    const float* __restrict__ sdtb, const float* __restrict__ Sb,
    const float* __restrict__ A_log, float* __restrict__ H0b)
{
    int t = blockIdx.x * 256 + threadIdx.x;   // 32768 = B_*512*16
    int n = t & 15;
    int d = (t >> 4) & 511;
    int b = t >> 13;
    float Av = -expf(A_log[d * 16 + n]);
    float h = 0.f;
    for (int c = 0; c < CH_; c++) {
        size_t base = (size_t)(b * CH_ + c) * 512 + d;
        H0b[base * 16 + n] = h;
        h = __expf(Av * sdtb[base]) * h + Sb[base * 16 + n];
    }
}

// ---------------- scan phase C: rescan + C-dot + D-skip + z-gate -> ym bf16 ---------
__global__ __launch_bounds__(256) void scan_phaseC(
    const float* __restrict__ dt, const float* __restrict__ xs,
    const float* __restrict__ dbc, const float* __restrict__ xz,
    const float* __restrict__ A_log, const float* __restrict__ Dp,
    const float* __restrict__ H0b, __hip_bfloat16* __restrict__ ymb, int dir)
{
    const int tid = threadIdx.x;
    const int d = blockIdx.x * 256 + tid;
    const int c = blockIdx.y;
    const int b = blockIdx.z;

    __shared__ float Ls[CL_][32];   // [j][0:16)=B, [j][16:32)=C
    {
        int j = tid >> 3, q = (tid & 7) * 4;
        int i = c * CL_ + j;
        int l = dir ? (L_ - 1 - i) : i;
        const float4 v = *(const float4*)&dbc[((size_t)(b * L_ + l)) * 64 + 32 + q];
        Ls[j][q] = v.x; Ls[j][q + 1] = v.y; Ls[j][q + 2] = v.z; Ls[j][q + 3] = v.w;
    }
    __syncthreads();

    float Av[16];
    {
        const float4* ap = (const float4*)&A_log[d * 16];
#pragma unroll
        for (int q = 0; q < 4; q++) {
            float4 a = ap[q];
            Av[q * 4 + 0] = -__expf(a.x);
            Av[q * 4 + 1] = -__expf(a.y);
            Av[q * 4 + 2] = -__expf(a.z);
            Av[q * 4 + 3] = -__expf(a.w);
        }
    }

    float h[16];
    {
        size_t base = (size_t)(b * CH_ + c) * 512 + d;
        const float4* Hp = (const float4*)&H0b[base * 16];
#pragma unroll
        for (int q = 0; q < 4; q++) {
            float4 v = Hp[q];
            h[q * 4 + 0] = v.x; h[q * 4 + 1] = v.y; h[q * 4 + 2] = v.z; h[q * 4 + 3] = v.w;
        }
    }
    const float Dv = Dp[d];

    const int i0 = c * CL_;
    const int l0 = dir ? (L_ - 1 - i0) : i0;
    const int stepE = dir ? -512 : 512;
    const int stepZ = dir ? -1024 : 1024;
    const float* pdt = dt + ((size_t)(b * L_ + l0)) * 512 + d;
    const float* pxs = xs + ((size_t)(b * L_ + l0)) * 512 + d;
    const float* pz  = xz + ((size_t)(b * L_ + l0)) * 1024 + 512 + d;
    __hip_bfloat16* pym = ymb + ((size_t)(b * L_ + l0)) * 512 + d;

    for (int half = 0; half < 2; half++) {
        float dbuf[16], xbuf[16], zbuf[16];
#pragma unroll
        for (int j = 0; j < 16; j++) {
            int jj = half * 16 + j;
            dbuf[j] = pdt[jj * stepE];
            xbuf[j] = pxs[jj * stepE];
            zbuf[j] = pz[jj * stepZ];
        }
#pragma unroll
        for (int j = 0; j < 16; j++) {
            int jj = half * 16 + j;
            float dtv = dbuf[j], xsv = xbuf[j];
            float u = dtv * xsv;
            float dot = 0.f;
#pragma unroll
            for (int n = 0; n < 16; n++) {
                h[n] = __expf(dtv * Av[n]) * h[n] + u * Ls[jj][n];
                dot += h[n] * Ls[jj][16 + n];
            }
            float y = dot + Dv * xsv;
            float zv = zbuf[j];
            y *= zv / (1.f + __expf(-zv));
            pym[jj * stepE] = __float2bfloat16(y);
        }
    }
}

extern "C" void kernel_launch(void* const* d_in, const int* in_sizes, int n_in,
                              void* d_out, int out_size, void* d_ws, size_t ws_size,
                              hipStream_t stream)
{
    const float* x = (const float*)d_in[0];
    float* out = (float*)d_out;

    // workspace layout
    float* ws  = (float*)d_ws;
    float* xz  = ws;                        // M_*1024 f32  (16MB)
    float* xs  = xz + (size_t)M_ * 1024;    // M_*512  f32  (8MB)
    float* dbc = xs + (size_t)M_ * 512;     // M_*64   f32  (1MB)
    float* dt  = dbc + (size_t)M_ * 64;     // M_*512  f32  (8MB)
    __hip_bfloat16* xb   = (__hip_bfloat16*)(dt + (size_t)M_ * 512); // M_*512 bf16
    __hip_bfloat16* ymb  = xb  + (size_t)M_ * 512;    // M_*512 bf16
    __hip_bfloat16* WinT = ymb + (size_t)M_ * 512;    // 1024*512 bf16
    __hip_bfloat16* WoutT= WinT + (size_t)1024 * 512; // 512*512 bf16
    float* sdtb = (float*)(WoutT + (size_t)512 * 512);        // B*CH*512
    float* Sb   = sdtb + (size_t)B_ * CH_ * 512;              // B*CH*512*16
    float* H0b  = Sb + (size_t)B_ * CH_ * 512 * 16;           // B*CH*512*16

    // x -> bf16 once (shared by both directions)
    cast_bf16<<<(M_ * 512) / 256, 256, 0, stream>>>(x, xb, M_ * 512);

    for (int dir = 0; dir < 2; dir++) {
        int wb = dir ? 10 : 1;
        const float* W_in    = (const float*)d_in[wb + 0];
        const float* W_conv  = (const float*)d_in[wb + 1];
        const float* b_conv  = (const float*)d_in[wb + 2];
        const float* W_xproj = (const float*)d_in[wb + 3];
        const float* W_dt    = (const float*)d_in[wb + 4];
        const float* b_dt    = (const float*)d_in[wb + 5];
        const float* A_log   = (const float*)d_in[wb + 6];
        const float* Dp      = (const float*)d_in[wb + 7];
        const float* W_out   = (const float*)d_in[wb + 8];

        transpose_cast<<<dim3(1024 / 32, 512 / 32), 256, 0, stream>>>(W_in, WinT, 512, 1024);
        transpose_cast<<<dim3(512 / 32, 512 / 32), 256, 0, stream>>>(W_out, WoutT, 512, 512);

        // 1. xz = x @ W_in   (bf16 MFMA)
        gemm_bt_bf16<<<dim3(1024 / 128, M_ / 128), 256, 0, stream>>>(
            (const short*)xb, (const short*)WinT, xz, M_, 1024, 512, 0);
        // 2. conv + silu -> xs
        conv_silu4<<<(M_ * 128) / 256, 256, 0, stream>>>(xz, W_conv, b_conv, xs, dir);
        // 3. dbc = xs @ W_xproj (fp32, 256-block specialized)
        xproj_gemm<<<M_ / 16, 256, 0, stream>>>(xs, W_xproj, dbc);
        // 4. dt (float4)
        dt_kernel4<<<(M_ * 128) / 256, 256, 0, stream>>>(dbc, W_dt, b_dt, dt);
        // 5. scan: phaseA -> combine -> phaseC
        scan_phaseA<<<dim3(2, CH_, B_), 256, 0, stream>>>(dt, xs, dbc, A_log, sdtb, Sb, dir);
        scan_combine<<<(B_ * 512 * 16) / 256, 256, 0, stream>>>(sdtb, Sb, A_log, H0b);
        scan_phaseC<<<dim3(2, CH_, B_), 256, 0, stream>>>(dt, xs, dbc, xz, A_log, Dp, H0b, ymb, dir);
        // 6. out (+)= ym @ W_out  (bf16 MFMA)
        gemm_bt_bf16<<<dim3(512 / 128, M_ / 128), 256, 0, stream>>>(
            (const short*)ymb, (const short*)WoutT, out, M_, 512, 512, dir);
    }
}

// Round 6
// 260.957 us; speedup vs baseline: 8.0345x; 1.3309x over previous
//
#include <hip/hip_runtime.h>
#include <hip/hip_bf16.h>
#include <math.h>

// Bidirectional Mamba: B=4 L=1024 DM=DI=512 N=16 K=4 R=32.
// R6: (a) both dirs batched into ONE xz GEMM (N=2048) and ONE out GEMM (K=1024,
//     beta=0); (b) GEMM gets double-buffered LDS + 1 barrier/iter (async loads
//     for k+1 fly during MFMA of k — critical at 1-2 blocks/CU); (c) all
//     elementwise/scan kernels process both dirs per launch (10 dispatches).

#define B_ 4
#define L_ 1024
#define NS_ 16
#define KC_ 4
#define RR_ 32
#define M_ (B_ * L_)   // 4096
#define CH_ 32         // scan chunks
#define CL_ 32         // steps per chunk

typedef short bf16x8 __attribute__((ext_vector_type(8)));
typedef float f32x4 __attribute__((ext_vector_type(4)));

__device__ inline void async_copy16(const void* g, void* l) {
    __builtin_amdgcn_global_load_lds((const __attribute__((address_space(1))) void*)g,
                                     (__attribute__((address_space(3))) void*)l, 16, 0, 0);
}

// ------- bf16 MFMA GEMM, double-buffered: C[M,N] f32 = A[M,K] @ BT[N,K] -------------
// 128x128 tile, K-step 32, 4 waves; one __syncthreads per k-iter; loads for k+1
// issued right after the barrier so they overlap ds_read+MFMA of tile k.
__global__ __launch_bounds__(256) void gemm_bt_bf16_db(
    const short* __restrict__ A, const short* __restrict__ BT,
    float* __restrict__ C, int M, int N, int K)
{
    __shared__ alignas(16) short lds[16384];   // 2 bufs x (A 4096 + B 4096 shorts)
    const int tid  = threadIdx.x;
    const int lane = tid & 63;
    const int w    = tid >> 6;
    const int wm   = (w >> 1) * 64;
    const int wn   = (w & 1) * 64;
    const int m0   = blockIdx.y * 128;
    const int n0   = blockIdx.x * 128;
    const int lg = lane >> 4;
    const int lr = lane & 15;

    f32x4 acc[4][4] = {};

    // prologue: stage tile 0 into buf 0
#pragma unroll
    for (int q = 0; q < 2; q++) {
        int c = q * 256 + tid;
        int r = c & 127, kg = c >> 7;
        async_copy16(&A[(size_t)(m0 + r) * K + kg * 8], &lds[(size_t)c * 8 - lane * 8]);
        async_copy16(&BT[(size_t)(n0 + r) * K + kg * 8], &lds[4096 + (size_t)c * 8 - lane * 8]);
    }

    for (int k0 = 0; k0 < K; k0 += 32) {
        const int p = (k0 >> 5) & 1;
        short* buf = &lds[p * 8192];
        __syncthreads();                          // drains tile-k loads (vmcnt) + prior ds_reads
        if (k0 + 32 < K) {
            short* nbuf = &lds[(p ^ 1) * 8192];
#pragma unroll
            for (int q = 0; q < 2; q++) {
                int c = q * 256 + tid;
                int r = c & 127, kg = c >> 7;
                async_copy16(&A[(size_t)(m0 + r) * K + k0 + 32 + kg * 8],
                             &nbuf[(size_t)c * 8 - lane * 8]);
                async_copy16(&BT[(size_t)(n0 + r) * K + k0 + 32 + kg * 8],
                             &nbuf[4096 + (size_t)c * 8 - lane * 8]);
            }
        }
        bf16x8 af[4], bf[4];
#pragma unroll
        for (int mt = 0; mt < 4; mt++)
            af[mt] = *(const bf16x8*)&buf[(lg * 128 + wm + mt * 16 + lr) * 8];
#pragma unroll
        for (int nt = 0; nt < 4; nt++)
            bf[nt] = *(const bf16x8*)&buf[4096 + (lg * 128 + wn + nt * 16 + lr) * 8];
#pragma unroll
        for (int mt = 0; mt < 4; mt++)
#pragma unroll
            for (int nt = 0; nt < 4; nt++)
                acc[mt][nt] = __builtin_amdgcn_mfma_f32_16x16x32_bf16(
                    af[mt], bf[nt], acc[mt][nt], 0, 0, 0);
    }

#pragma unroll
    for (int mt = 0; mt < 4; mt++)
#pragma unroll
        for (int nt = 0; nt < 4; nt++)
#pragma unroll
            for (int r = 0; r < 4; r++) {
                int m = m0 + wm + mt * 16 + lg * 4 + r;
                int n = n0 + wn + nt * 16 + lr;
                C[(size_t)m * N + n] = acc[mt][nt][r];
            }
}

// ---------------- cast fp32 -> bf16 ------------------------------------------------
__global__ __launch_bounds__(256) void cast_bf16(const float* __restrict__ src,
                                                 __hip_bfloat16* __restrict__ dst, int n)
{
    int i = blockIdx.x * 256 + threadIdx.x;
    if (i < n) dst[i] = __float2bfloat16(src[i]);
}

// ---------------- transpose-cast: W[K][N] f32 -> WT[N][ldT] bf16 -------------------
__global__ __launch_bounds__(256) void transpose_cast(
    const float* __restrict__ W, __hip_bfloat16* __restrict__ WT, int K, int N, int ldT)
{
    __shared__ float tile[32][33];
    int k0 = blockIdx.y * 32, n0 = blockIdx.x * 32;
    int tx = threadIdx.x & 31, ty = threadIdx.x >> 5;
#pragma unroll
    for (int i = 0; i < 4; i++)
        tile[ty + i * 8][tx] = W[(size_t)(k0 + ty + i * 8) * N + n0 + tx];
    __syncthreads();
#pragma unroll
    for (int i = 0; i < 4; i++)
        WT[(size_t)(n0 + ty + i * 8) * ldT + k0 + tx] =
            __float2bfloat16(tile[tx][ty + i * 8]);
}

// ---------------- conv + bias + SiLU -> xs, both dirs ------------------------------
__global__ __launch_bounds__(256) void conv_silu4(
    const float* __restrict__ xzc, const float* __restrict__ WcF,
    const float* __restrict__ WcB, const float* __restrict__ bcF,
    const float* __restrict__ bcB, float* __restrict__ xs2)
{
    const int dir = blockIdx.y;
    const float* Wc = dir ? WcB : WcF;
    const float* bc = dir ? bcB : bcF;
    float* xs = xs2 + (size_t)dir * M_ * 512;

    int idx = blockIdx.x * 256 + threadIdx.x;     // over M_*128
    int d4 = (idx & 127) * 4;
    int bl = idx >> 7;
    int l  = bl & (L_ - 1);
    int b  = bl >> 10;

    float4 acc = *(const float4*)&bc[d4];
    float wA[4][4];
#pragma unroll
    for (int i = 0; i < 4; i++) {
        float4 t = *(const float4*)&Wc[(d4 + i) * 4];
        wA[i][0] = t.x; wA[i][1] = t.y; wA[i][2] = t.z; wA[i][3] = t.w;
    }
#pragma unroll
    for (int k = 0; k < KC_; k++) {
        int ls = dir ? (l + 3 - k) : (l - 3 + k);
        if (ls >= 0 && ls < L_) {
            float4 xv = *(const float4*)&xzc[((size_t)(b * L_ + ls)) * 2048 + dir * 1024 + d4];
            acc.x += xv.x * wA[0][k];
            acc.y += xv.y * wA[1][k];
            acc.z += xv.z * wA[2][k];
            acc.w += xv.w * wA[3][k];
        }
    }
    float4 o;
    o.x = acc.x / (1.f + __expf(-acc.x));
    o.y = acc.y / (1.f + __expf(-acc.y));
    o.z = acc.z / (1.f + __expf(-acc.z));
    o.w = acc.w / (1.f + __expf(-acc.w));
    *(float4*)&xs[(size_t)bl * 512 + d4] = o;
}

// ---------------- xproj: dbc[M,64] = xs[M,512] @ Wx[512,64], both dirs --------------
__global__ __launch_bounds__(256) void xproj_gemm(
    const float* __restrict__ xs2, const float* __restrict__ WxF,
    const float* __restrict__ WxB, float* __restrict__ dbc2)
{
    const int dir = blockIdx.y;
    const float* A = xs2 + (size_t)dir * M_ * 512;
    const float* W = dir ? WxB : WxF;
    float* Cc = dbc2 + (size_t)dir * M_ * 64;

    __shared__ float Ws[64][64];
    __shared__ float As[16][64];
    const int t = threadIdx.x;
    const int row0 = blockIdx.x * 16;
    const int r  = t >> 4;
    const int n4 = (t & 15) * 4;

    float4 acc = make_float4(0.f, 0.f, 0.f, 0.f);

    for (int k0 = 0; k0 < 512; k0 += 64) {
#pragma unroll
        for (int i = 0; i < 4; i++) {
            int f = t + 256 * i;
            *(float4*)&Ws[f >> 4][(f & 15) * 4] =
                *(const float4*)&W[(size_t)(k0 + (f >> 4)) * 64 + (f & 15) * 4];
        }
        *(float4*)&As[t >> 4][(t & 15) * 4] =
            *(const float4*)&A[(size_t)(row0 + (t >> 4)) * 512 + k0 + (t & 15) * 4];
        __syncthreads();

#pragma unroll
        for (int kk4 = 0; kk4 < 16; kk4++) {
            float4 av = *(const float4*)&As[r][kk4 * 4];
            float4 w0 = *(const float4*)&Ws[kk4 * 4 + 0][n4];
            acc.x += av.x * w0.x; acc.y += av.x * w0.y; acc.z += av.x * w0.z; acc.w += av.x * w0.w;
            float4 w1 = *(const float4*)&Ws[kk4 * 4 + 1][n4];
            acc.x += av.y * w1.x; acc.y += av.y * w1.y; acc.z += av.y * w1.z; acc.w += av.y * w1.w;
            float4 w2 = *(const float4*)&Ws[kk4 * 4 + 2][n4];
            acc.x += av.z * w2.x; acc.y += av.z * w2.y; acc.z += av.z * w2.z; acc.w += av.z * w2.w;
            float4 w3 = *(const float4*)&Ws[kk4 * 4 + 3][n4];
            acc.x += av.w * w3.x; acc.y += av.w * w3.y; acc.z += av.w * w3.z; acc.w += av.w * w3.w;
        }
        __syncthreads();
    }

    *(float4*)&Cc[(size_t)(row0 + r) * 64 + n4] = acc;
}

// ---------------- dt = softplus(dt_in @ W_dt + b_dt), both dirs --------------------
__global__ __launch_bounds__(256) void dt_kernel4(
    const float* __restrict__ dbc2, const float* __restrict__ WdtF,
    const float* __restrict__ WdtB, const float* __restrict__ bdtF,
    const float* __restrict__ bdtB, float* __restrict__ dt2)
{
    const int dir = blockIdx.y;
    const float* dbc = dbc2 + (size_t)dir * M_ * 64;
    const float* Wdt = dir ? WdtB : WdtF;
    const float* bdt = dir ? bdtB : bdtF;
    float* dt = dt2 + (size_t)dir * M_ * 512;

    int idx = blockIdx.x * 256 + threadIdx.x;   // over M_*128
    int d4  = (idx & 127) * 4;
    int row = idx >> 7;
    float4 acc = *(const float4*)&bdt[d4];
    const float* dr = &dbc[(size_t)row * 64];
#pragma unroll
    for (int k = 0; k < RR_; k += 4) {
        float4 dv = *(const float4*)&dr[k];
        float4 w0 = *(const float4*)&Wdt[(size_t)(k + 0) * 512 + d4];
        acc.x += dv.x * w0.x; acc.y += dv.x * w0.y; acc.z += dv.x * w0.z; acc.w += dv.x * w0.w;
        float4 w1 = *(const float4*)&Wdt[(size_t)(k + 1) * 512 + d4];
        acc.x += dv.y * w1.x; acc.y += dv.y * w1.y; acc.z += dv.y * w1.z; acc.w += dv.y * w1.w;
        float4 w2 = *(const float4*)&Wdt[(size_t)(k + 2) * 512 + d4];
        acc.x += dv.z * w2.x; acc.y += dv.z * w2.y; acc.z += dv.z * w2.z; acc.w += dv.z * w2.w;
        float4 w3 = *(const float4*)&Wdt[(size_t)(k + 3) * 512 + d4];
        acc.x += dv.w * w3.x; acc.y += dv.w * w3.y; acc.z += dv.w * w3.z; acc.w += dv.w * w3.w;
    }
    float4 o;
    o.x = (acc.x > 20.f) ? acc.x : log1pf(expf(acc.x));
    o.y = (acc.y > 20.f) ? acc.y : log1pf(expf(acc.y));
    o.z = (acc.z > 20.f) ? acc.z : log1pf(expf(acc.z));
    o.w = (acc.w > 20.f) ? acc.w : log1pf(expf(acc.w));
    *(float4*)&dt[(size_t)row * 512 + d4] = o;
}

// ---------------- scan phase A: per-chunk summaries, both dirs ----------------------
// grid (4, CH_, B_): dir = bx>>1, d-half = bx&1.
__global__ __launch_bounds__(256) void scan_phaseA(
    const float* __restrict__ dt2, const float* __restrict__ xs2,
    const float* __restrict__ dbc2, const float* __restrict__ AlF,
    const float* __restrict__ AlB, float* __restrict__ sdtb2,
    float* __restrict__ Sb2)
{
    const int dir = blockIdx.x >> 1;
    const float* dt  = dt2  + (size_t)dir * M_ * 512;
    const float* xs  = xs2  + (size_t)dir * M_ * 512;
    const float* dbc = dbc2 + (size_t)dir * M_ * 64;
    const float* A_log = dir ? AlB : AlF;
    float* sdtb = sdtb2 + (size_t)dir * B_ * CH_ * 512;
    float* Sb   = Sb2   + (size_t)dir * B_ * CH_ * 512 * 16;

    const int tid = threadIdx.x;
    const int d = (blockIdx.x & 1) * 256 + tid;
    const int c = blockIdx.y;
    const int b = blockIdx.z;

    __shared__ float Bs[CL_][16];
    {
        int j = tid >> 3, n2 = (tid & 7) * 2;
        int i = c * CL_ + j;
        int l = dir ? (L_ - 1 - i) : i;
        const float2 v = *(const float2*)&dbc[((size_t)(b * L_ + l)) * 64 + 32 + n2];
        Bs[j][n2] = v.x; Bs[j][n2 + 1] = v.y;
    }
    __syncthreads();

    float Av[16];
    {
        const float4* ap = (const float4*)&A_log[d * 16];
#pragma unroll
        for (int q = 0; q < 4; q++) {
            float4 a = ap[q];
            Av[q * 4 + 0] = -__expf(a.x);
            Av[q * 4 + 1] = -__expf(a.y);
            Av[q * 4 + 2] = -__expf(a.z);
            Av[q * 4 + 3] = -__expf(a.w);
        }
    }

    const int i0 = c * CL_;
    const int l0 = dir ? (L_ - 1 - i0) : i0;
    const int stepE = dir ? -512 : 512;
    const float* pdt = dt + ((size_t)(b * L_ + l0)) * 512 + d;
    const float* pxs = xs + ((size_t)(b * L_ + l0)) * 512 + d;

    float h[16];
#pragma unroll
    for (int n = 0; n < 16; n++) h[n] = 0.f;
    float sdt = 0.f;

    for (int half = 0; half < 2; half++) {
        float dbuf[16], xbuf[16];
#pragma unroll
        for (int j = 0; j < 16; j++) {
            int jj = half * 16 + j;
            dbuf[j] = pdt[jj * stepE];
            xbuf[j] = pxs[jj * stepE];
        }
#pragma unroll
        for (int j = 0; j < 16; j++) {
            int jj = half * 16 + j;
            float dtv = dbuf[j], xsv = xbuf[j];
            float u = dtv * xsv;
            sdt += dtv;
#pragma unroll
            for (int n = 0; n < 16; n++)
                h[n] = __expf(dtv * Av[n]) * h[n] + u * Bs[jj][n];
        }
    }

    size_t base = (size_t)(b * CH_ + c) * 512 + d;
    sdtb[base] = sdt;
    float4* Sp = (float4*)&Sb[base * 16];
#pragma unroll
    for (int q = 0; q < 4; q++)
        Sp[q] = make_float4(h[q * 4], h[q * 4 + 1], h[q * 4 + 2], h[q * 4 + 3]);
}

// ---------------- scan combine: chunk entry states, both dirs ----------------------
__global__ __launch_bounds__(256) void scan_combine(
    const float* __restrict__ sdtb2, const float* __restrict__ Sb2,
    const float* __restrict__ AlF, const float* __restrict__ AlB,
    float* __restrict__ H0b2)
{
    const int dir = blockIdx.y;
    const float* sdtb = sdtb2 + (size_t)dir * B_ * CH_ * 512;
    const float* Sb   = Sb2   + (size_t)dir * B_ * CH_ * 512 * 16;
    const float* A_log = dir ? AlB : AlF;
    float* H0b = H0b2 + (size_t)dir * B_ * CH_ * 512 * 16;

    int t = blockIdx.x * 256 + threadIdx.x;   // 32768 = B_*512*16
    int n = t & 15;
    int d = (t >> 4) & 511;
    int b = t >> 13;
    float Av = -expf(A_log[d * 16 + n]);
    float h = 0.f;
    for (int c = 0; c < CH_; c++) {
        size_t base = (size_t)(b * CH_ + c) * 512 + d;
        H0b[base * 16 + n] = h;
        h = __expf(Av * sdtb[base]) * h + Sb[base * 16 + n];
    }
}

// ---------------- scan phase C: rescan + C-dot + D-skip + z-gate -> ymcat bf16 ------
__global__ __launch_bounds__(256) void scan_phaseC(
    const float* __restrict__ dt2, const float* __restrict__ xs2,
    const float* __restrict__ dbc2, const float* __restrict__ xzc,
    const float* __restrict__ AlF, const float* __restrict__ AlB,
    const float* __restrict__ DF, const float* __restrict__ DB,
    const float* __restrict__ H0b2, __hip_bfloat16* __restrict__ ymcat)
{
    const int dir = blockIdx.x >> 1;
    const float* dt  = dt2  + (size_t)dir * M_ * 512;
    const float* xs  = xs2  + (size_t)dir * M_ * 512;
    const float* dbc = dbc2 + (size_t)dir * M_ * 64;
    const float* A_log = dir ? AlB : AlF;
    const float* Dp    = dir ? DB : DF;
    const float* H0b = H0b2 + (size_t)dir * B_ * CH_ * 512 * 16;

    const int tid = threadIdx.x;
    const int d = (blockIdx.x & 1) * 256 + tid;
    const int c = blockIdx.y;
    const int b = blockIdx.z;

    __shared__ float Ls[CL_][32];   // [j][0:16)=B, [j][16:32)=C
    {
        int j = tid >> 3, q = (tid & 7) * 4;
        int i = c * CL_ + j;
        int l = dir ? (L_ - 1 - i) : i;
        const float4 v = *(const float4*)&dbc[((size_t)(b * L_ + l)) * 64 + 32 + q];
        Ls[j][q] = v.x; Ls[j][q + 1] = v.y; Ls[j][q + 2] = v.z; Ls[j][q + 3] = v.w;
    }
    __syncthreads();

    float Av[16];
    {
        const float4* ap = (const float4*)&A_log[d * 16];
#pragma unroll
        for (int q = 0; q < 4; q++) {
            float4 a = ap[q];
            Av[q * 4 + 0] = -__expf(a.x);
            Av[q * 4 + 1] = -__expf(a.y);
            Av[q * 4 + 2] = -__expf(a.z);
            Av[q * 4 + 3] = -__expf(a.w);
        }
    }

    float h[16];
    {
        size_t base = (size_t)(b * CH_ + c) * 512 + d;
        const float4* Hp = (const float4*)&H0b[base * 16];
#pragma unroll
        for (int q = 0; q < 4; q++) {
            float4 v = Hp[q];
            h[q * 4 + 0] = v.x; h[q * 4 + 1] = v.y; h[q * 4 + 2] = v.z; h[q * 4 + 3] = v.w;
        }
    }
    const float Dv = Dp[d];

    const int i0 = c * CL_;
    const int l0 = dir ? (L_ - 1 - i0) : i0;
    const int stepE = dir ? -512 : 512;
    const int stepZ = dir ? -2048 : 2048;
    const int stepY = dir ? -1024 : 1024;
    const float* pdt = dt + ((size_t)(b * L_ + l0)) * 512 + d;
    const float* pxs = xs + ((size_t)(b * L_ + l0)) * 512 + d;
    const float* pz  = xzc + ((size_t)(b * L_ + l0)) * 2048 + dir * 1024 + 512 + d;
    __hip_bfloat16* pym = ymcat + ((size_t)(b * L_ + l0)) * 1024 + dir * 512 + d;

    for (int half = 0; half < 2; half++) {
        float dbuf[16], xbuf[16], zbuf[16];
#pragma unroll
        for (int j = 0; j < 16; j++) {
            int jj = half * 16 + j;
            dbuf[j] = pdt[jj * stepE];
            xbuf[j] = pxs[jj * stepE];
            zbuf[j] = pz[jj * stepZ];
        }
#pragma unroll
        for (int j = 0; j < 16; j++) {
            int jj = half * 16 + j;
            float dtv = dbuf[j], xsv = xbuf[j];
            float u = dtv * xsv;
            float dot = 0.f;
#pragma unroll
            for (int n = 0; n < 16; n++) {
                h[n] = __expf(dtv * Av[n]) * h[n] + u * Ls[jj][n];
                dot += h[n] * Ls[jj][16 + n];
            }
            float y = dot + Dv * xsv;
            float zv = zbuf[j];
            y *= zv / (1.f + __expf(-zv));
            pym[jj * stepY] = __float2bfloat16(y);
        }
    }
}

extern "C" void kernel_launch(void* const* d_in, const int* in_sizes, int n_in,
                              void* d_out, int out_size, void* d_ws, size_t ws_size,
                              hipStream_t stream)
{
    const float* x = (const float*)d_in[0];
    float* out = (float*)d_out;

    const float* W_in_f    = (const float*)d_in[1];
    const float* W_conv_f  = (const float*)d_in[2];
    const float* b_conv_f  = (const float*)d_in[3];
    const float* W_xproj_f = (const float*)d_in[4];
    const float* W_dt_f    = (const float*)d_in[5];
    const float* b_dt_f    = (const float*)d_in[6];
    const float* A_log_f   = (const float*)d_in[7];
    const float* D_f       = (const float*)d_in[8];
    const float* W_out_f   = (const float*)d_in[9];
    const float* W_in_b    = (const float*)d_in[10];
    const float* W_conv_b  = (const float*)d_in[11];
    const float* b_conv_b  = (const float*)d_in[12];
    const float* W_xproj_b = (const float*)d_in[13];
    const float* W_dt_b    = (const float*)d_in[14];
    const float* b_dt_b    = (const float*)d_in[15];
    const float* A_log_b   = (const float*)d_in[16];
    const float* D_b       = (const float*)d_in[17];
    const float* W_out_b   = (const float*)d_in[18];

    // workspace layout (floats)
    float* ws    = (float*)d_ws;
    float* xzc   = ws;                                  // M*2048           (32MB)
    float* xs2   = xzc  + (size_t)M_ * 2048;            // 2*M*512          (16MB)
    float* dbc2  = xs2  + (size_t)2 * M_ * 512;         // 2*M*64           (2MB)
    float* dt2   = dbc2 + (size_t)2 * M_ * 64;          // 2*M*512          (16MB)
    float* sdtb2 = dt2  + (size_t)2 * M_ * 512;         // 2*B*CH*512       (0.5MB)
    float* Sb2   = sdtb2 + (size_t)2 * B_ * CH_ * 512;  // 2*B*CH*512*16    (8MB)
    float* H0b2  = Sb2  + (size_t)2 * B_ * CH_ * 512 * 16;  // same         (8MB)
    __hip_bfloat16* xb    = (__hip_bfloat16*)(H0b2 + (size_t)2 * B_ * CH_ * 512 * 16);
    __hip_bfloat16* ymcat = xb + (size_t)M_ * 512;      // M*1024 bf16      (8MB)
    __hip_bfloat16* WinTc = ymcat + (size_t)M_ * 1024;  // 2048*512 bf16    (2MB)
    __hip_bfloat16* BToutc= WinTc + (size_t)2048 * 512; // 512*1024 bf16    (1MB)

    // x -> bf16
    cast_bf16<<<(M_ * 512) / 256, 256, 0, stream>>>(x, xb, M_ * 512);

    // weight transpose-casts: WinTc rows 0..1023 = f, 1024..2047 = b (ldT=512)
    transpose_cast<<<dim3(32, 16), 256, 0, stream>>>(W_in_f, WinTc, 512, 1024, 512);
    transpose_cast<<<dim3(32, 16), 256, 0, stream>>>(W_in_b, WinTc + (size_t)1024 * 512, 512, 1024, 512);
    // BToutc[n][k]: k<512 = W_out_f[k][n], k>=512 = W_out_b[k-512][n] (ldT=1024)
    transpose_cast<<<dim3(16, 16), 256, 0, stream>>>(W_out_f, BToutc, 512, 512, 1024);
    transpose_cast<<<dim3(16, 16), 256, 0, stream>>>(W_out_b, BToutc + 512, 512, 512, 1024);

    // 1. xz_cat = xb @ [W_in_f | W_in_b]   (M x 2048, K=512) — 512 blocks
    gemm_bt_bf16_db<<<dim3(2048 / 128, M_ / 128), 256, 0, stream>>>(
        (const short*)xb, (const short*)WinTc, xzc, M_, 2048, 512);
    // 2. conv + silu -> xs (both dirs)
    conv_silu4<<<dim3((M_ * 128) / 256, 2), 256, 0, stream>>>(
        xzc, W_conv_f, W_conv_b, b_conv_f, b_conv_b, xs2);
    // 3. dbc = xs @ W_xproj (both dirs)
    xproj_gemm<<<dim3(M_ / 16, 2), 256, 0, stream>>>(xs2, W_xproj_f, W_xproj_b, dbc2);
    // 4. dt (both dirs)
    dt_kernel4<<<dim3((M_ * 128) / 256, 2), 256, 0, stream>>>(
        dbc2, W_dt_f, W_dt_b, b_dt_f, b_dt_b, dt2);
    // 5. scan (both dirs per launch)
    scan_phaseA<<<dim3(4, CH_, B_), 256, 0, stream>>>(dt2, xs2, dbc2, A_log_f, A_log_b, sdtb2, Sb2);
    scan_combine<<<dim3(128, 2), 256, 0, stream>>>(sdtb2, Sb2, A_log_f, A_log_b, H0b2);
    scan_phaseC<<<dim3(4, CH_, B_), 256, 0, stream>>>(
        dt2, xs2, dbc2, xzc, A_log_f, A_log_b, D_f, D_b, H0b2, ymcat);
    // 6. out = ymcat @ [W_out_f ; W_out_b]   (M x 512, K=1024, beta=0) — one launch
    gemm_bt_bf16_db<<<dim3(512 / 128, M_ / 128), 256, 0, stream>>>(
        (const short*)ymcat, (const short*)BToutc, out, M_, 512, 1024);
}